// Round 3
// baseline (472.482 us; speedup 1.0000x reference)
//
#include <hip/hip_runtime.h>
#include <math.h>

#define BB 16
#define NN 1024
#define DD 768
#define KK 8
#define BETA_F 0.5f
#define EPS_F 1e-8f

// ---------------------------------------------------------------------------
// Kernel 1: exact top-9 nearest neighbors (by d2, tie-break lower index),
// drop slot 0 (self), store 8 neighbor indices per point.
// One thread per point; centers + sq staged in LDS; top-9 kept as sortable
// 64-bit keys in registers (static indexing only -> no scratch).
// ---------------------------------------------------------------------------
__global__ __launch_bounds__(256) void topk_kernel(const float* __restrict__ centers,
                                                   int* __restrict__ idx_out) {
    __shared__ float2 c_lds[NN];
    __shared__ float  sq_lds[NN];
    const int b     = blockIdx.x >> 2;        // NN/256 = 4 chunks per batch
    const int chunk = blockIdx.x & 3;
    const int tid   = threadIdx.x;

    // stage centers[b] (1024 x float2 = 512 x float4)
    const float4* cbase = (const float4*)(centers + (size_t)b * NN * 2);
    for (int i = tid; i < NN / 2; i += 256) {
        float4 v = cbase[i];
        c_lds[2 * i + 0] = make_float2(v.x, v.y);
        c_lds[2 * i + 1] = make_float2(v.z, v.w);
    }
    __syncthreads();
    for (int i = tid; i < NN; i += 256) {
        float2 c = c_lds[i];
        sq_lds[i] = c.x * c.x + c.y * c.y;
    }
    __syncthreads();

    const int   n   = chunk * 256 + tid;
    const float2 an = c_lds[n];
    const float sqn = sq_lds[n];

    unsigned long long best[9];
#pragma unroll
    for (int s = 0; s < 9; ++s) best[s] = ~0ULL;

    for (int m = 0; m < NN; ++m) {
        float2 cm = c_lds[m];
        float dot = an.x * cm.x + an.y * cm.y;
        float d2  = (sqn + sq_lds[m]) - 2.0f * dot;
        // monotone float->uint map (handles possible tiny negative d2)
        unsigned int u = __float_as_uint(d2);
        u ^= (unsigned int)((int)u >> 31) | 0x80000000u;
        unsigned long long ck = ((unsigned long long)u << 10) | (unsigned int)m;
        if (ck < best[8]) {
#pragma unroll
            for (int s = 0; s < 9; ++s) {
                unsigned long long lo = ck < best[s] ? ck : best[s];
                unsigned long long hi = ck < best[s] ? best[s] : ck;
                best[s] = lo;
                ck = hi;
            }
        }
    }

    int* out = idx_out + ((size_t)b * NN + n) * KK;
#pragma unroll
    for (int s = 0; s < KK; ++s) out[s] = (int)(best[s + 1] & 1023ULL);
}

// ---------------------------------------------------------------------------
// Kernel 2: per-row inverse norms for student and teacher. One wave per row.
// ---------------------------------------------------------------------------
__global__ __launch_bounds__(256) void norm_kernel(const float* __restrict__ s,
                                                   const float* __restrict__ t,
                                                   float* __restrict__ inv_s,
                                                   float* __restrict__ inv_t) {
    const int row  = blockIdx.x * 4 + (threadIdx.x >> 6);
    const int lane = threadIdx.x & 63;
    const float4* srow = (const float4*)(s + (size_t)row * DD);
    const float4* trow = (const float4*)(t + (size_t)row * DD);
    float ss = 0.f, tt = 0.f;
#pragma unroll
    for (int i = 0; i < 3; ++i) {
        float4 v = srow[lane + 64 * i];
        ss = fmaf(v.x, v.x, fmaf(v.y, v.y, fmaf(v.z, v.z, fmaf(v.w, v.w, ss))));
        float4 w = trow[lane + 64 * i];
        tt = fmaf(w.x, w.x, fmaf(w.y, w.y, fmaf(w.z, w.z, fmaf(w.w, w.w, tt))));
    }
#pragma unroll
    for (int m = 1; m < 64; m <<= 1) {
        ss += __shfl_xor(ss, m);
        tt += __shfl_xor(tt, m);
    }
    if (lane == 0) {
        inv_s[row] = 1.0f / fmaxf(sqrtf(ss), EPS_F);
        inv_t[row] = 1.0f / fmaxf(sqrtf(tt), EPS_F);
    }
}

// ---------------------------------------------------------------------------
// Kernel 3: cosine relations + smooth-L1, one wave per (b,n), 8 neighbors.
// Anchor rows (student+teacher) live in registers; two 64-lane butterfly
// reductions per neighbor; one float atomic per wave.
// ---------------------------------------------------------------------------
__global__ __launch_bounds__(256) void loss_kernel(const float* __restrict__ s,
                                                   const float* __restrict__ t,
                                                   const int* __restrict__ idx,
                                                   const float* __restrict__ inv_s,
                                                   const float* __restrict__ inv_t,
                                                   float* __restrict__ accum) {
    const int p    = blockIdx.x * 4 + (threadIdx.x >> 6);  // point in [0, B*N)
    const int lane = threadIdx.x & 63;
    const int base = (p >> 10) << 10;                      // b * N

    const float4* srow = (const float4*)(s + (size_t)p * DD);
    const float4* trow = (const float4*)(t + (size_t)p * DD);
    float4 as0 = srow[lane], as1 = srow[lane + 64], as2 = srow[lane + 128];
    float4 at0 = trow[lane], at1 = trow[lane + 64], at2 = trow[lane + 128];

    const float isn = inv_s[p];
    const float itn = inv_t[p];

    float sum = 0.f;
#pragma unroll
    for (int j = 0; j < KK; ++j) {
        const int q = base + idx[p * KK + j];
        const float4* snb = (const float4*)(s + (size_t)q * DD);
        const float4* tnb = (const float4*)(t + (size_t)q * DD);
        float ds = 0.f, dt = 0.f;
        float4 v, w;
        v = snb[lane];
        ds = fmaf(as0.x, v.x, fmaf(as0.y, v.y, fmaf(as0.z, v.z, fmaf(as0.w, v.w, ds))));
        v = snb[lane + 64];
        ds = fmaf(as1.x, v.x, fmaf(as1.y, v.y, fmaf(as1.z, v.z, fmaf(as1.w, v.w, ds))));
        v = snb[lane + 128];
        ds = fmaf(as2.x, v.x, fmaf(as2.y, v.y, fmaf(as2.z, v.z, fmaf(as2.w, v.w, ds))));
        w = tnb[lane];
        dt = fmaf(at0.x, w.x, fmaf(at0.y, w.y, fmaf(at0.z, w.z, fmaf(at0.w, w.w, dt))));
        w = tnb[lane + 64];
        dt = fmaf(at1.x, w.x, fmaf(at1.y, w.y, fmaf(at1.z, w.z, fmaf(at1.w, w.w, dt))));
        w = tnb[lane + 128];
        dt = fmaf(at2.x, w.x, fmaf(at2.y, w.y, fmaf(at2.z, w.z, fmaf(at2.w, w.w, dt))));
#pragma unroll
        for (int m = 1; m < 64; m <<= 1) {
            ds += __shfl_xor(ds, m);
            dt += __shfl_xor(dt, m);
        }
        const float cs   = ds * isn * inv_s[q];
        const float ct   = dt * itn * inv_t[q];
        const float diff = fabsf(cs - ct);
        const float sl1  = diff < BETA_F ? (0.5f * diff * diff / BETA_F)
                                         : (diff - 0.5f * BETA_F);
        sum += sl1;
    }
    if (lane == 0) atomicAdd(accum, sum);
}

__global__ void finalize_kernel(const float* __restrict__ accum, float* __restrict__ out) {
    // 1 / (B*N*K) = 2^-17, exact
    out[0] = accum[0] * (1.0f / (float)(BB * NN * KK));
}

extern "C" void kernel_launch(void* const* d_in, const int* in_sizes, int n_in,
                              void* d_out, int out_size, void* d_ws, size_t ws_size,
                              hipStream_t stream) {
    const float* student = (const float*)d_in[0];
    const float* teacher = (const float*)d_in[1];
    const float* centers = (const float*)d_in[2];
    float* out = (float*)d_out;

    // workspace layout
    int*   idx_buf = (int*)d_ws;                               // 16*1024*8 ints = 512 KB
    float* inv_s   = (float*)((char*)d_ws + (size_t)BB * NN * KK * sizeof(int));
    float* inv_t   = inv_s + BB * NN;                          // 64 KB each
    float* accum   = inv_t + BB * NN;                          // 4 B

    hipMemsetAsync(accum, 0, sizeof(float), stream);

    topk_kernel<<<BB * (NN / 256), 256, 0, stream>>>(centers, idx_buf);
    norm_kernel<<<(BB * NN) / 4, 256, 0, stream>>>(student, teacher, inv_s, inv_t);
    loss_kernel<<<(BB * NN) / 4, 256, 0, stream>>>(student, teacher, idx_buf,
                                                   inv_s, inv_t, accum);
    finalize_kernel<<<1, 1, 0, stream>>>(accum, out);
}

// Round 4
// 181.854 us; speedup vs baseline: 2.5981x; 2.5981x over previous
//
#include <hip/hip_runtime.h>
#include <math.h>

#define BB 16
#define NN 1024
#define DD 768
#define KK 8
#define BETA_F 0.5f
#define EPS_F 1e-8f

// ---------------------------------------------------------------------------
// Kernel 1: exact top-9 NN (key = (monotone(d2)<<10)|index, ascending).
// 8 threads per point, each scans 128 candidates keeping a sorted top-9 in
// registers (static indexing only); 8 partial lists merged via LDS.
// Result is bit-identical to a single-thread full scan (total order on keys).
// ---------------------------------------------------------------------------
#define TPK_PTS 32
#define TPK_SEG 8
__global__ __launch_bounds__(256) void topk_kernel(const float* __restrict__ centers,
                                                   int* __restrict__ idx_out) {
    __shared__ float2 c_lds[NN];
    __shared__ float  sq_lds[NN];
    __shared__ unsigned long long keys[TPK_PTS][TPK_SEG][9];
    const int b   = blockIdx.x >> 5;   // 32 blocks per batch
    const int blk = blockIdx.x & 31;
    const int tid = threadIdx.x;
    const int pl  = tid >> 3;          // local point 0..31
    const int seg = tid & 7;           // candidate segment 0..7

    const float4* cbase = (const float4*)(centers + (size_t)b * NN * 2);
    for (int i = tid; i < NN / 2; i += 256) {
        float4 v = cbase[i];
        c_lds[2 * i + 0] = make_float2(v.x, v.y);
        c_lds[2 * i + 1] = make_float2(v.z, v.w);
    }
    __syncthreads();
    for (int i = tid; i < NN; i += 256) {
        float2 c = c_lds[i];
        sq_lds[i] = c.x * c.x + c.y * c.y;
    }
    __syncthreads();

    const int    n   = blk * TPK_PTS + pl;
    const float2 an  = c_lds[n];
    const float  sqn = sq_lds[n];

    unsigned long long best[9];
#pragma unroll
    for (int s2 = 0; s2 < 9; ++s2) best[s2] = ~0ULL;

    const int m0 = seg * 128;
    for (int m = m0; m < m0 + 128; ++m) {
        float2 cm = c_lds[m];
        float dot = an.x * cm.x + an.y * cm.y;
        float d2  = (sqn + sq_lds[m]) - 2.0f * dot;
        unsigned int u = __float_as_uint(d2);
        u ^= (unsigned int)((int)u >> 31) | 0x80000000u;
        unsigned long long ck = ((unsigned long long)u << 10) | (unsigned int)m;
        if (ck < best[8]) {
#pragma unroll
            for (int s2 = 0; s2 < 9; ++s2) {
                unsigned long long lo = ck < best[s2] ? ck : best[s2];
                unsigned long long hi = ck < best[s2] ? best[s2] : ck;
                best[s2] = lo;
                ck = hi;
            }
        }
    }
#pragma unroll
    for (int s2 = 0; s2 < 9; ++s2) keys[pl][seg][s2] = best[s2];
    __syncthreads();

    if (seg == 0) {
#pragma unroll
        for (int o = 1; o < TPK_SEG; ++o) {
#pragma unroll
            for (int e = 0; e < 9; ++e) {
                unsigned long long ck = keys[pl][o][e];
                if (ck < best[8]) {
#pragma unroll
                    for (int s2 = 0; s2 < 9; ++s2) {
                        unsigned long long lo = ck < best[s2] ? ck : best[s2];
                        unsigned long long hi = ck < best[s2] ? best[s2] : ck;
                        best[s2] = lo;
                        ck = hi;
                    }
                }
            }
        }
        int* outp = idx_out + ((size_t)b * NN + n) * KK;
#pragma unroll
        for (int s2 = 0; s2 < KK; ++s2) outp[s2] = (int)(best[s2 + 1] & 1023ULL);
    }
}

// ---------------------------------------------------------------------------
// Kernel 2: per-row inverse norms (student, teacher). One wave per row.
// ---------------------------------------------------------------------------
__global__ __launch_bounds__(256) void norm_kernel(const float* __restrict__ s,
                                                   const float* __restrict__ t,
                                                   float* __restrict__ inv_s,
                                                   float* __restrict__ inv_t) {
    const int row  = blockIdx.x * 4 + (threadIdx.x >> 6);
    const int lane = threadIdx.x & 63;
    const float4* srow = (const float4*)(s + (size_t)row * DD);
    const float4* trow = (const float4*)(t + (size_t)row * DD);
    float ss = 0.f, tt = 0.f;
#pragma unroll
    for (int i = 0; i < 3; ++i) {
        float4 v = srow[lane + 64 * i];
        ss = fmaf(v.x, v.x, fmaf(v.y, v.y, fmaf(v.z, v.z, fmaf(v.w, v.w, ss))));
        float4 w = trow[lane + 64 * i];
        tt = fmaf(w.x, w.x, fmaf(w.y, w.y, fmaf(w.z, w.z, fmaf(w.w, w.w, tt))));
    }
#pragma unroll
    for (int m = 1; m < 64; m <<= 1) {
        ss += __shfl_xor(ss, m);
        tt += __shfl_xor(tt, m);
    }
    if (lane == 0) {
        inv_s[row] = 1.0f / fmaxf(sqrtf(ss), EPS_F);
        inv_t[row] = 1.0f / fmaxf(sqrtf(tt), EPS_F);
    }
}

// ---------------------------------------------------------------------------
// Kernel 3: cosine relations + smooth-L1. One wave per point. All 8 neighbor
// dot-pairs accumulated into independent registers (ILP), ONE batched 16-chain
// butterfly reduce, per-block partial sum -> part[] (no global atomics).
// ---------------------------------------------------------------------------
__global__ __launch_bounds__(256) void loss_kernel(const float* __restrict__ s,
                                                   const float* __restrict__ t,
                                                   const int* __restrict__ idx,
                                                   const float* __restrict__ inv_s,
                                                   const float* __restrict__ inv_t,
                                                   float* __restrict__ part) {
    const int wave = threadIdx.x >> 6;
    const int lane = threadIdx.x & 63;
    const int p    = blockIdx.x * 4 + wave;
    const int base = p & ~(NN - 1);

    int q[8];
    {
        const int4* ip = (const int4*)(idx + (size_t)p * KK);
        int4 a = ip[0], c = ip[1];
        q[0] = base + a.x; q[1] = base + a.y; q[2] = base + a.z; q[3] = base + a.w;
        q[4] = base + c.x; q[5] = base + c.y; q[6] = base + c.z; q[7] = base + c.w;
    }
    float isq[8], itq[8];
#pragma unroll
    for (int j = 0; j < 8; ++j) { isq[j] = inv_s[q[j]]; itq[j] = inv_t[q[j]]; }
    const float isn = inv_s[p];
    const float itn = inv_t[p];

    const float4* srow = (const float4*)(s + (size_t)p * DD);
    const float4* trow = (const float4*)(t + (size_t)p * DD);
    float4 as0 = srow[lane], as1 = srow[lane + 64], as2 = srow[lane + 128];
    float4 at0 = trow[lane], at1 = trow[lane + 64], at2 = trow[lane + 128];

    float ds[8], dt[8];
#pragma unroll
    for (int j = 0; j < 8; ++j) {
        const float4* snb = (const float4*)(s + (size_t)q[j] * DD);
        const float4* tnb = (const float4*)(t + (size_t)q[j] * DD);
        float4 v0 = snb[lane], v1 = snb[lane + 64], v2 = snb[lane + 128];
        float4 w0 = tnb[lane], w1 = tnb[lane + 64], w2 = tnb[lane + 128];
        float a = 0.f, bsum = 0.f;
        a = fmaf(as0.x, v0.x, a); a = fmaf(as0.y, v0.y, a);
        a = fmaf(as0.z, v0.z, a); a = fmaf(as0.w, v0.w, a);
        a = fmaf(as1.x, v1.x, a); a = fmaf(as1.y, v1.y, a);
        a = fmaf(as1.z, v1.z, a); a = fmaf(as1.w, v1.w, a);
        a = fmaf(as2.x, v2.x, a); a = fmaf(as2.y, v2.y, a);
        a = fmaf(as2.z, v2.z, a); a = fmaf(as2.w, v2.w, a);
        bsum = fmaf(at0.x, w0.x, bsum); bsum = fmaf(at0.y, w0.y, bsum);
        bsum = fmaf(at0.z, w0.z, bsum); bsum = fmaf(at0.w, w0.w, bsum);
        bsum = fmaf(at1.x, w1.x, bsum); bsum = fmaf(at1.y, w1.y, bsum);
        bsum = fmaf(at1.z, w1.z, bsum); bsum = fmaf(at1.w, w1.w, bsum);
        bsum = fmaf(at2.x, w2.x, bsum); bsum = fmaf(at2.y, w2.y, bsum);
        bsum = fmaf(at2.z, w2.z, bsum); bsum = fmaf(at2.w, w2.w, bsum);
        ds[j] = a;
        dt[j] = bsum;
    }
    // one batched butterfly over 16 independent chains
#pragma unroll
    for (int m = 1; m < 64; m <<= 1) {
#pragma unroll
        for (int j = 0; j < 8; ++j) {
            ds[j] += __shfl_xor(ds[j], m);
            dt[j] += __shfl_xor(dt[j], m);
        }
    }
    float sum = 0.f;
#pragma unroll
    for (int j = 0; j < 8; ++j) {
        const float cs   = ds[j] * isn * isq[j];
        const float ct   = dt[j] * itn * itq[j];
        const float diff = fabsf(cs - ct);
        sum += diff < BETA_F ? (0.5f * diff * diff / BETA_F) : (diff - 0.5f * BETA_F);
    }

    __shared__ float wpart[4];
    if (lane == 0) wpart[wave] = sum;
    __syncthreads();
    if (threadIdx.x == 0)
        part[blockIdx.x] = (wpart[0] + wpart[1]) + (wpart[2] + wpart[3]);
}

// ---------------------------------------------------------------------------
// Kernel 4: deterministic tree reduce of 4096 block partials + final scale.
// ---------------------------------------------------------------------------
__global__ __launch_bounds__(256) void finalize_kernel(const float* __restrict__ part,
                                                       float* __restrict__ out) {
    __shared__ float red[256];
    float acc = 0.f;
    for (int i = threadIdx.x; i < (BB * NN) / 4; i += 256) acc += part[i];
    red[threadIdx.x] = acc;
    __syncthreads();
    for (int off = 128; off > 0; off >>= 1) {
        if (threadIdx.x < off) red[threadIdx.x] += red[threadIdx.x + off];
        __syncthreads();
    }
    if (threadIdx.x == 0) out[0] = red[0] * (1.0f / (float)(BB * NN * KK));
}

extern "C" void kernel_launch(void* const* d_in, const int* in_sizes, int n_in,
                              void* d_out, int out_size, void* d_ws, size_t ws_size,
                              hipStream_t stream) {
    const float* student = (const float*)d_in[0];
    const float* teacher = (const float*)d_in[1];
    const float* centers = (const float*)d_in[2];
    float* out = (float*)d_out;

    // workspace layout
    int*   idx_buf = (int*)d_ws;                                        // 512 KB
    float* inv_s   = (float*)((char*)d_ws + (size_t)BB * NN * KK * sizeof(int));
    float* inv_t   = inv_s + BB * NN;                                   // 64 KB each
    float* part    = inv_t + BB * NN;                                   // 16 KB

    topk_kernel<<<BB * (NN / TPK_PTS), 256, 0, stream>>>(centers, idx_buf);
    norm_kernel<<<(BB * NN) / 4, 256, 0, stream>>>(student, teacher, inv_s, inv_t);
    loss_kernel<<<(BB * NN) / 4, 256, 0, stream>>>(student, teacher, idx_buf,
                                                   inv_s, inv_t, part);
    finalize_kernel<<<1, 256, 0, stream>>>(part, out);
}

// Round 5
// 135.056 us; speedup vs baseline: 3.4984x; 1.3465x over previous
//
#include <hip/hip_runtime.h>
#include <hip/hip_fp16.h>
#include <math.h>

#define BB 16
#define NN 1024
#define DD 768
#define KK 8
#define BETA_F 0.5f
#define EPS_F 1e-8f

typedef _Float16 h2_t __attribute__((ext_vector_type(2)));

#if defined(__has_builtin)
#if __has_builtin(__builtin_amdgcn_fdot2)
#define HAVE_FDOT2 1
#endif
#endif

// acc += dot of 4 halves packed in uint2 (v_dot2_f32_f16 x2, or unpack-fma fallback)
__device__ __forceinline__ float dot4acc(uint2 a, uint2 b, float acc) {
#ifdef HAVE_FDOT2
    acc = __builtin_amdgcn_fdot2(__builtin_bit_cast(h2_t, a.x),
                                 __builtin_bit_cast(h2_t, b.x), acc, false);
    acc = __builtin_amdgcn_fdot2(__builtin_bit_cast(h2_t, a.y),
                                 __builtin_bit_cast(h2_t, b.y), acc, false);
#else
    float2 fa = __half22float2(__builtin_bit_cast(__half2, a.x));
    float2 fb = __half22float2(__builtin_bit_cast(__half2, b.x));
    acc = fmaf(fa.x, fb.x, acc); acc = fmaf(fa.y, fb.y, acc);
    fa = __half22float2(__builtin_bit_cast(__half2, a.y));
    fb = __half22float2(__builtin_bit_cast(__half2, b.y));
    acc = fmaf(fa.x, fb.x, acc); acc = fmaf(fa.y, fb.y, acc);
#endif
    return acc;
}

// ---------------------------------------------------------------------------
// Kernel 1: exact top-9 NN (key = (monotone(d2)<<10)|index) — unchanged from
// round 4 (proven bit-exact, absmax 0.0).
// ---------------------------------------------------------------------------
#define TPK_PTS 32
#define TPK_SEG 8
__global__ __launch_bounds__(256) void topk_kernel(const float* __restrict__ centers,
                                                   int* __restrict__ idx_out) {
    __shared__ float2 c_lds[NN];
    __shared__ float  sq_lds[NN];
    __shared__ unsigned long long keys[TPK_PTS][TPK_SEG][9];
    const int b   = blockIdx.x >> 5;
    const int blk = blockIdx.x & 31;
    const int tid = threadIdx.x;
    const int pl  = tid >> 3;
    const int seg = tid & 7;

    const float4* cbase = (const float4*)(centers + (size_t)b * NN * 2);
    for (int i = tid; i < NN / 2; i += 256) {
        float4 v = cbase[i];
        c_lds[2 * i + 0] = make_float2(v.x, v.y);
        c_lds[2 * i + 1] = make_float2(v.z, v.w);
    }
    __syncthreads();
    for (int i = tid; i < NN; i += 256) {
        float2 c = c_lds[i];
        sq_lds[i] = c.x * c.x + c.y * c.y;
    }
    __syncthreads();

    const int    n   = blk * TPK_PTS + pl;
    const float2 an  = c_lds[n];
    const float  sqn = sq_lds[n];

    unsigned long long best[9];
#pragma unroll
    for (int s2 = 0; s2 < 9; ++s2) best[s2] = ~0ULL;

    const int m0 = seg * 128;
    for (int m = m0; m < m0 + 128; ++m) {
        float2 cm = c_lds[m];
        float dot = an.x * cm.x + an.y * cm.y;
        float d2  = (sqn + sq_lds[m]) - 2.0f * dot;
        unsigned int u = __float_as_uint(d2);
        u ^= (unsigned int)((int)u >> 31) | 0x80000000u;
        unsigned long long ck = ((unsigned long long)u << 10) | (unsigned int)m;
        if (ck < best[8]) {
#pragma unroll
            for (int s2 = 0; s2 < 9; ++s2) {
                unsigned long long lo = ck < best[s2] ? ck : best[s2];
                unsigned long long hi = ck < best[s2] ? best[s2] : ck;
                best[s2] = lo;
                ck = hi;
            }
        }
    }
#pragma unroll
    for (int s2 = 0; s2 < 9; ++s2) keys[pl][seg][s2] = best[s2];
    __syncthreads();

    if (seg == 0) {
#pragma unroll
        for (int o = 1; o < TPK_SEG; ++o) {
#pragma unroll
            for (int e = 0; e < 9; ++e) {
                unsigned long long ck = keys[pl][o][e];
                if (ck < best[8]) {
#pragma unroll
                    for (int s2 = 0; s2 < 9; ++s2) {
                        unsigned long long lo = ck < best[s2] ? ck : best[s2];
                        unsigned long long hi = ck < best[s2] ? best[s2] : ck;
                        best[s2] = lo;
                        ck = hi;
                    }
                }
            }
        }
        int* outp = idx_out + ((size_t)b * NN + n) * KK;
#pragma unroll
        for (int s2 = 0; s2 < KK; ++s2) outp[s2] = (int)(best[s2 + 1] & 1023ULL);
    }
}

// ---------------------------------------------------------------------------
// Kernel 2 (fp16 path): row-normalize s,t in fp32 and emit normalized fp16.
// One wave per row.
// ---------------------------------------------------------------------------
__global__ __launch_bounds__(256) void normh_kernel(const float* __restrict__ s,
                                                    const float* __restrict__ t,
                                                    __half* __restrict__ ns,
                                                    __half* __restrict__ nt) {
    const int row  = blockIdx.x * 4 + (threadIdx.x >> 6);
    const int lane = threadIdx.x & 63;
    const float4* srow = (const float4*)(s + (size_t)row * DD);
    const float4* trow = (const float4*)(t + (size_t)row * DD);
    float4 vs[3], vt[3];
    float ss = 0.f, tt = 0.f;
#pragma unroll
    for (int i = 0; i < 3; ++i) {
        vs[i] = srow[lane + 64 * i];
        vt[i] = trow[lane + 64 * i];
        ss = fmaf(vs[i].x, vs[i].x, fmaf(vs[i].y, vs[i].y,
             fmaf(vs[i].z, vs[i].z, fmaf(vs[i].w, vs[i].w, ss))));
        tt = fmaf(vt[i].x, vt[i].x, fmaf(vt[i].y, vt[i].y,
             fmaf(vt[i].z, vt[i].z, fmaf(vt[i].w, vt[i].w, tt))));
    }
#pragma unroll
    for (int m = 1; m < 64; m <<= 1) {
        ss += __shfl_xor(ss, m);
        tt += __shfl_xor(tt, m);
    }
    const float is_ = 1.0f / fmaxf(sqrtf(ss), EPS_F);
    const float it_ = 1.0f / fmaxf(sqrtf(tt), EPS_F);

    uint2* nsrow = (uint2*)(ns + (size_t)row * DD);
    uint2* ntrow = (uint2*)(nt + (size_t)row * DD);
#pragma unroll
    for (int i = 0; i < 3; ++i) {
        __half2 a0 = __floats2half2_rn(vs[i].x * is_, vs[i].y * is_);
        __half2 a1 = __floats2half2_rn(vs[i].z * is_, vs[i].w * is_);
        __half2 b0 = __floats2half2_rn(vt[i].x * it_, vt[i].y * it_);
        __half2 b1 = __floats2half2_rn(vt[i].z * it_, vt[i].w * it_);
        uint2 ua; ua.x = __builtin_bit_cast(unsigned int, a0);
        ua.y = __builtin_bit_cast(unsigned int, a1);
        uint2 ub; ub.x = __builtin_bit_cast(unsigned int, b0);
        ub.y = __builtin_bit_cast(unsigned int, b1);
        nsrow[lane + 64 * i] = ua;
        ntrow[lane + 64 * i] = ub;
    }
}

// ---------------------------------------------------------------------------
// Kernel 3 (fp16 path): gather normalized fp16 rows, dot -> cosines directly,
// smooth-L1, per-block partial. XCD batch-affinity swizzle: each XCD walks
// 2 whole batches (3 MB fp16 working set < 4 MB per-XCD L2).
// ---------------------------------------------------------------------------
__global__ __launch_bounds__(256) void lossh_kernel(const __half* __restrict__ ns,
                                                    const __half* __restrict__ nt,
                                                    const int* __restrict__ idx,
                                                    float* __restrict__ part) {
    const int bid  = blockIdx.x;
    const int v    = (bid & 7) * 512 + (bid >> 3);   // bijective, nwg%8==0
    const int wave = threadIdx.x >> 6;
    const int lane = threadIdx.x & 63;
    const int p    = v * 4 + wave;
    const int base = p & ~(NN - 1);

    int q[8];
    {
        const int4* ip = (const int4*)(idx + (size_t)p * KK);
        int4 a = ip[0], c = ip[1];
        q[0] = base + a.x; q[1] = base + a.y; q[2] = base + a.z; q[3] = base + a.w;
        q[4] = base + c.x; q[5] = base + c.y; q[6] = base + c.z; q[7] = base + c.w;
    }

    const uint2* srow = (const uint2*)(ns + (size_t)p * DD);
    const uint2* trow = (const uint2*)(nt + (size_t)p * DD);
    uint2 sa[3], ta[3];
#pragma unroll
    for (int c = 0; c < 3; ++c) {
        sa[c] = srow[lane + 64 * c];
        ta[c] = trow[lane + 64 * c];
    }

    // prefetch all 8 neighbors' s+t chunks (48 x uint2, static indices)
    uint2 sv[8][3], tv[8][3];
#pragma unroll
    for (int j = 0; j < 8; ++j) {
        const uint2* snb = (const uint2*)(ns + (size_t)q[j] * DD);
        const uint2* tnb = (const uint2*)(nt + (size_t)q[j] * DD);
#pragma unroll
        for (int c = 0; c < 3; ++c) {
            sv[j][c] = snb[lane + 64 * c];
            tv[j][c] = tnb[lane + 64 * c];
        }
    }

    float ds[8], dt[8];
#pragma unroll
    for (int j = 0; j < 8; ++j) {
        float a = 0.f, b = 0.f;
#pragma unroll
        for (int c = 0; c < 3; ++c) {
            a = dot4acc(sa[c], sv[j][c], a);
            b = dot4acc(ta[c], tv[j][c], b);
        }
        ds[j] = a;
        dt[j] = b;
    }
#pragma unroll
    for (int m = 1; m < 64; m <<= 1) {
#pragma unroll
        for (int j = 0; j < 8; ++j) {
            ds[j] += __shfl_xor(ds[j], m);
            dt[j] += __shfl_xor(dt[j], m);
        }
    }
    float sum = 0.f;
#pragma unroll
    for (int j = 0; j < 8; ++j) {
        const float diff = fabsf(ds[j] - dt[j]);     // rows pre-normalized
        sum += diff < BETA_F ? (0.5f * diff * diff / BETA_F) : (diff - 0.5f * BETA_F);
    }

    __shared__ float wpart[4];
    if (lane == 0) wpart[wave] = sum;
    __syncthreads();
    if (threadIdx.x == 0)
        part[v] = (wpart[0] + wpart[1]) + (wpart[2] + wpart[3]);
}

// ---------------------------------------------------------------------------
// f32 fallback path (round-4 kernels), used only if ws_size is too small.
// ---------------------------------------------------------------------------
__global__ __launch_bounds__(256) void norm_kernel(const float* __restrict__ s,
                                                   const float* __restrict__ t,
                                                   float* __restrict__ inv_s,
                                                   float* __restrict__ inv_t) {
    const int row  = blockIdx.x * 4 + (threadIdx.x >> 6);
    const int lane = threadIdx.x & 63;
    const float4* srow = (const float4*)(s + (size_t)row * DD);
    const float4* trow = (const float4*)(t + (size_t)row * DD);
    float ss = 0.f, tt = 0.f;
#pragma unroll
    for (int i = 0; i < 3; ++i) {
        float4 v = srow[lane + 64 * i];
        ss = fmaf(v.x, v.x, fmaf(v.y, v.y, fmaf(v.z, v.z, fmaf(v.w, v.w, ss))));
        float4 w = trow[lane + 64 * i];
        tt = fmaf(w.x, w.x, fmaf(w.y, w.y, fmaf(w.z, w.z, fmaf(w.w, w.w, tt))));
    }
#pragma unroll
    for (int m = 1; m < 64; m <<= 1) {
        ss += __shfl_xor(ss, m);
        tt += __shfl_xor(tt, m);
    }
    if (lane == 0) {
        inv_s[row] = 1.0f / fmaxf(sqrtf(ss), EPS_F);
        inv_t[row] = 1.0f / fmaxf(sqrtf(tt), EPS_F);
    }
}

__global__ __launch_bounds__(256) void lossf_kernel(const float* __restrict__ s,
                                                    const float* __restrict__ t,
                                                    const int* __restrict__ idx,
                                                    const float* __restrict__ inv_s,
                                                    const float* __restrict__ inv_t,
                                                    float* __restrict__ part) {
    const int wave = threadIdx.x >> 6;
    const int lane = threadIdx.x & 63;
    const int p    = blockIdx.x * 4 + wave;
    const int base = p & ~(NN - 1);
    int q[8];
    {
        const int4* ip = (const int4*)(idx + (size_t)p * KK);
        int4 a = ip[0], c = ip[1];
        q[0] = base + a.x; q[1] = base + a.y; q[2] = base + a.z; q[3] = base + a.w;
        q[4] = base + c.x; q[5] = base + c.y; q[6] = base + c.z; q[7] = base + c.w;
    }
    float isq[8], itq[8];
#pragma unroll
    for (int j = 0; j < 8; ++j) { isq[j] = inv_s[q[j]]; itq[j] = inv_t[q[j]]; }
    const float isn = inv_s[p];
    const float itn = inv_t[p];
    const float4* srow = (const float4*)(s + (size_t)p * DD);
    const float4* trow = (const float4*)(t + (size_t)p * DD);
    float4 as0 = srow[lane], as1 = srow[lane + 64], as2 = srow[lane + 128];
    float4 at0 = trow[lane], at1 = trow[lane + 64], at2 = trow[lane + 128];
    float ds[8], dt[8];
#pragma unroll
    for (int j = 0; j < 8; ++j) {
        const float4* snb = (const float4*)(s + (size_t)q[j] * DD);
        const float4* tnb = (const float4*)(t + (size_t)q[j] * DD);
        float4 v0 = snb[lane], v1 = snb[lane + 64], v2 = snb[lane + 128];
        float4 w0 = tnb[lane], w1 = tnb[lane + 64], w2 = tnb[lane + 128];
        float a = 0.f, b = 0.f;
        a = fmaf(as0.x, v0.x, a); a = fmaf(as0.y, v0.y, a);
        a = fmaf(as0.z, v0.z, a); a = fmaf(as0.w, v0.w, a);
        a = fmaf(as1.x, v1.x, a); a = fmaf(as1.y, v1.y, a);
        a = fmaf(as1.z, v1.z, a); a = fmaf(as1.w, v1.w, a);
        a = fmaf(as2.x, v2.x, a); a = fmaf(as2.y, v2.y, a);
        a = fmaf(as2.z, v2.z, a); a = fmaf(as2.w, v2.w, a);
        b = fmaf(at0.x, w0.x, b); b = fmaf(at0.y, w0.y, b);
        b = fmaf(at0.z, w0.z, b); b = fmaf(at0.w, w0.w, b);
        b = fmaf(at1.x, w1.x, b); b = fmaf(at1.y, w1.y, b);
        b = fmaf(at1.z, w1.z, b); b = fmaf(at1.w, w1.w, b);
        b = fmaf(at2.x, w2.x, b); b = fmaf(at2.y, w2.y, b);
        b = fmaf(at2.z, w2.z, b); b = fmaf(at2.w, w2.w, b);
        ds[j] = a; dt[j] = b;
    }
#pragma unroll
    for (int m = 1; m < 64; m <<= 1) {
#pragma unroll
        for (int j = 0; j < 8; ++j) {
            ds[j] += __shfl_xor(ds[j], m);
            dt[j] += __shfl_xor(dt[j], m);
        }
    }
    float sum = 0.f;
#pragma unroll
    for (int j = 0; j < 8; ++j) {
        const float cs   = ds[j] * isn * isq[j];
        const float ct   = dt[j] * itn * itq[j];
        const float diff = fabsf(cs - ct);
        sum += diff < BETA_F ? (0.5f * diff * diff / BETA_F) : (diff - 0.5f * BETA_F);
    }
    __shared__ float wpart[4];
    if (lane == 0) wpart[wave] = sum;
    __syncthreads();
    if (threadIdx.x == 0)
        part[blockIdx.x] = (wpart[0] + wpart[1]) + (wpart[2] + wpart[3]);
}

// ---------------------------------------------------------------------------
// Kernel 4: deterministic tree reduce of 4096 block partials + final scale.
// ---------------------------------------------------------------------------
__global__ __launch_bounds__(256) void finalize_kernel(const float* __restrict__ part,
                                                       float* __restrict__ out) {
    __shared__ float red[256];
    float acc = 0.f;
    for (int i = threadIdx.x; i < (BB * NN) / 4; i += 256) acc += part[i];
    red[threadIdx.x] = acc;
    __syncthreads();
    for (int off = 128; off > 0; off >>= 1) {
        if (threadIdx.x < off) red[threadIdx.x] += red[threadIdx.x + off];
        __syncthreads();
    }
    if (threadIdx.x == 0) out[0] = red[0] * (1.0f / (float)(BB * NN * KK));
}

extern "C" void kernel_launch(void* const* d_in, const int* in_sizes, int n_in,
                              void* d_out, int out_size, void* d_ws, size_t ws_size,
                              hipStream_t stream) {
    const float* student = (const float*)d_in[0];
    const float* teacher = (const float*)d_in[1];
    const float* centers = (const float*)d_in[2];
    float* out = (float*)d_out;

    const size_t idx_bytes  = (size_t)BB * NN * KK * sizeof(int);      // 512 KB
    const size_t half_bytes = (size_t)BB * NN * DD * sizeof(__half);   // 25.2 MB
    const size_t part_bytes = 4096 * sizeof(float);
    int* idx_buf = (int*)d_ws;

    topk_kernel<<<BB * (NN / TPK_PTS), 256, 0, stream>>>(centers, idx_buf);

    if (ws_size >= idx_bytes + 2 * half_bytes + part_bytes) {
        __half* ns  = (__half*)((char*)d_ws + idx_bytes);
        __half* nt  = ns + (size_t)BB * NN * DD;
        float* part = (float*)((char*)d_ws + idx_bytes + 2 * half_bytes);
        normh_kernel<<<(BB * NN) / 4, 256, 0, stream>>>(student, teacher, ns, nt);
        lossh_kernel<<<(BB * NN) / 4, 256, 0, stream>>>(ns, nt, idx_buf, part);
        finalize_kernel<<<1, 256, 0, stream>>>(part, out);
    } else {
        float* inv_s = (float*)((char*)d_ws + idx_bytes);
        float* inv_t = inv_s + BB * NN;
        float* part  = inv_t + BB * NN;
        norm_kernel<<<(BB * NN) / 4, 256, 0, stream>>>(student, teacher, inv_s, inv_t);
        lossf_kernel<<<(BB * NN) / 4, 256, 0, stream>>>(student, teacher, idx_buf,
                                                        inv_s, inv_t, part);
        finalize_kernel<<<1, 256, 0, stream>>>(part, out);
    }
}

// Round 6
// 105.602 us; speedup vs baseline: 4.4742x; 1.2789x over previous
//
#include <hip/hip_runtime.h>
#include <hip/hip_fp16.h>
#include <math.h>

#define BB 16
#define NN 1024
#define DD 768
#define KK 8
#define BETA_F 0.5f
#define EPS_F 1e-8f

#define TPK_PTS 32
#define TPK_SEG 8
#define TPK_BLOCKS (BB * (NN / TPK_PTS))   // 512
#define NORM_BLOCKS ((BB * NN) / 4)        // 4096

typedef _Float16 h2_t __attribute__((ext_vector_type(2)));

#if defined(__has_builtin)
#if __has_builtin(__builtin_amdgcn_fdot2)
#define HAVE_FDOT2 1
#endif
#endif

// acc += dot of 4 halves packed in uint2 (v_dot2_f32_f16 x2, or unpack-fma fallback)
__device__ __forceinline__ float dot4acc(uint2 a, uint2 b, float acc) {
#ifdef HAVE_FDOT2
    acc = __builtin_amdgcn_fdot2(__builtin_bit_cast(h2_t, a.x),
                                 __builtin_bit_cast(h2_t, b.x), acc, false);
    acc = __builtin_amdgcn_fdot2(__builtin_bit_cast(h2_t, a.y),
                                 __builtin_bit_cast(h2_t, b.y), acc, false);
#else
    float2 fa = __half22float2(__builtin_bit_cast(__half2, a.x));
    float2 fb = __half22float2(__builtin_bit_cast(__half2, b.x));
    acc = fmaf(fa.x, fb.x, acc); acc = fmaf(fa.y, fb.y, acc);
    fa = __half22float2(__builtin_bit_cast(__half2, a.y));
    fb = __half22float2(__builtin_bit_cast(__half2, b.y));
    acc = fmaf(fa.x, fb.x, acc); acc = fmaf(fa.y, fb.y, acc);
#endif
    return acc;
}

// ---------------------------------------------------------------------------
// topk helpers: exact top-9 NN, key = (monotone(d2)<<10)|index, ascending.
// Same arithmetic as rounds 2-5 (proven bit-exact, absmax 0.0); only the
// scan partition / LDS layout changed (order-independent under total order).
// ---------------------------------------------------------------------------
__device__ __forceinline__ void topk_insert9(unsigned long long ck,
                                             unsigned long long* best) {
    if (ck < best[8]) {
#pragma unroll
        for (int s2 = 0; s2 < 9; ++s2) {
            unsigned long long lo = ck < best[s2] ? ck : best[s2];
            unsigned long long hi = ck < best[s2] ? best[s2] : ck;
            best[s2] = lo;
            ck = hi;
        }
    }
}

__device__ __forceinline__ unsigned long long topk_key(float anx, float any_,
                                                       float sqn, float4 c, int m) {
    float dot = anx * c.x + any_ * c.y;
    float d2  = (sqn + c.z) - 2.0f * dot;
    unsigned int u = __float_as_uint(d2);
    u ^= (unsigned int)((int)u >> 31) | 0x80000000u;
    return ((unsigned long long)u << 10) | (unsigned int)m;
}

// c4: [NN] packed (x, y, x^2+y^2, 0); keys: [TPK_PTS][TPK_SEG][9]
__device__ __forceinline__ void topk_body(const float* __restrict__ centers,
                                          int* __restrict__ idx_out,
                                          int tkb, int tid, float4* c4,
                                          unsigned long long (*keys)[TPK_SEG][9]) {
    const int b   = tkb >> 5;          // 32 topk blocks per batch
    const int blk = tkb & 31;
    const int pl  = tid >> 3;          // local point 0..31
    const int seg = tid & 7;           // candidate segment 0..7

    const float4* cbase = (const float4*)(centers + (size_t)b * NN * 2);
    for (int i = tid; i < NN / 2; i += 256) {
        float4 v = cbase[i];
        c4[2 * i + 0] = make_float4(v.x, v.y, v.x * v.x + v.y * v.y, 0.f);
        c4[2 * i + 1] = make_float4(v.z, v.w, v.z * v.z + v.w * v.w, 0.f);
    }
    __syncthreads();

    const int    n   = blk * TPK_PTS + pl;
    const float4 cn  = c4[n];
    const float  anx = cn.x, any_ = cn.y, sqn = cn.z;

    unsigned long long best[9];
#pragma unroll
    for (int s2 = 0; s2 < 9; ++s2) best[s2] = ~0ULL;

    // interleaved partition: lane scans m = i*8 + seg  (conflict-free: bank 4*seg)
    // unroll x4: all 4 ds_read_b128 issued before the insert chains.
    for (int it = 0; it < 32; ++it) {
        const int mb = it * 32 + seg;
        float4 c0 = c4[mb];
        float4 c1 = c4[mb + 8];
        float4 c2 = c4[mb + 16];
        float4 c3 = c4[mb + 24];
        unsigned long long k0 = topk_key(anx, any_, sqn, c0, mb);
        unsigned long long k1 = topk_key(anx, any_, sqn, c1, mb + 8);
        unsigned long long k2 = topk_key(anx, any_, sqn, c2, mb + 16);
        unsigned long long k3 = topk_key(anx, any_, sqn, c3, mb + 24);
        topk_insert9(k0, best);
        topk_insert9(k1, best);
        topk_insert9(k2, best);
        topk_insert9(k3, best);
    }

#pragma unroll
    for (int s2 = 0; s2 < 9; ++s2) keys[pl][seg][s2] = best[s2];
    __syncthreads();

    if (seg == 0) {
#pragma unroll
        for (int o = 1; o < TPK_SEG; ++o)
#pragma unroll
            for (int e = 0; e < 9; ++e)
                topk_insert9(keys[pl][o][e], best);
        int* outp = idx_out + ((size_t)b * NN + n) * KK;
#pragma unroll
        for (int s2 = 0; s2 < KK; ++s2) outp[s2] = (int)(best[s2 + 1] & 1023ULL);
    }
}

// ---------------------------------------------------------------------------
// normh body: row-normalize s,t in fp32, emit normalized fp16. One wave/row.
// ---------------------------------------------------------------------------
__device__ __forceinline__ void normh_body(const float* __restrict__ s,
                                           const float* __restrict__ t,
                                           __half* __restrict__ ns,
                                           __half* __restrict__ nt,
                                           int nb, int tid) {
    const int row  = nb * 4 + (tid >> 6);
    const int lane = tid & 63;
    const float4* srow = (const float4*)(s + (size_t)row * DD);
    const float4* trow = (const float4*)(t + (size_t)row * DD);
    float4 vs[3], vt[3];
    float ss = 0.f, tt = 0.f;
#pragma unroll
    for (int i = 0; i < 3; ++i) {
        vs[i] = srow[lane + 64 * i];
        vt[i] = trow[lane + 64 * i];
        ss = fmaf(vs[i].x, vs[i].x, fmaf(vs[i].y, vs[i].y,
             fmaf(vs[i].z, vs[i].z, fmaf(vs[i].w, vs[i].w, ss))));
        tt = fmaf(vt[i].x, vt[i].x, fmaf(vt[i].y, vt[i].y,
             fmaf(vt[i].z, vt[i].z, fmaf(vt[i].w, vt[i].w, tt))));
    }
#pragma unroll
    for (int m = 1; m < 64; m <<= 1) {
        ss += __shfl_xor(ss, m);
        tt += __shfl_xor(tt, m);
    }
    const float is_ = 1.0f / fmaxf(sqrtf(ss), EPS_F);
    const float it_ = 1.0f / fmaxf(sqrtf(tt), EPS_F);

    uint2* nsrow = (uint2*)(ns + (size_t)row * DD);
    uint2* ntrow = (uint2*)(nt + (size_t)row * DD);
#pragma unroll
    for (int i = 0; i < 3; ++i) {
        __half2 a0 = __floats2half2_rn(vs[i].x * is_, vs[i].y * is_);
        __half2 a1 = __floats2half2_rn(vs[i].z * is_, vs[i].w * is_);
        __half2 b0 = __floats2half2_rn(vt[i].x * it_, vt[i].y * it_);
        __half2 b1 = __floats2half2_rn(vt[i].z * it_, vt[i].w * it_);
        uint2 ua; ua.x = __builtin_bit_cast(unsigned int, a0);
        ua.y = __builtin_bit_cast(unsigned int, a1);
        uint2 ub; ub.x = __builtin_bit_cast(unsigned int, b0);
        ub.y = __builtin_bit_cast(unsigned int, b1);
        nsrow[lane + 64 * i] = ua;
        ntrow[lane + 64 * i] = ub;
    }
}

// ---------------------------------------------------------------------------
// Fused kernel: blocks [0,512) run topk (VALU/LDS-bound), blocks [512,4608)
// run normh (HBM-bound). Independent work, complementary pipes -> overlap.
// topk first so the longer pole starts immediately.
// ---------------------------------------------------------------------------
__global__ __launch_bounds__(256) void fused_prep(const float* __restrict__ centers,
                                                  const float* __restrict__ s,
                                                  const float* __restrict__ t,
                                                  int* __restrict__ idx_out,
                                                  __half* __restrict__ ns,
                                                  __half* __restrict__ nt) {
    __shared__ float4 c4[NN];                              // 16 KB
    __shared__ unsigned long long keys[TPK_PTS][TPK_SEG][9]; // 18 KB
    if (blockIdx.x < TPK_BLOCKS)
        topk_body(centers, idx_out, blockIdx.x, threadIdx.x, c4, keys);
    else
        normh_body(s, t, ns, nt, blockIdx.x - TPK_BLOCKS, threadIdx.x);
}

// standalone topk for the f32 fallback path
__global__ __launch_bounds__(256) void topk_kernel(const float* __restrict__ centers,
                                                   int* __restrict__ idx_out) {
    __shared__ float4 c4[NN];
    __shared__ unsigned long long keys[TPK_PTS][TPK_SEG][9];
    topk_body(centers, idx_out, blockIdx.x, threadIdx.x, c4, keys);
}

// ---------------------------------------------------------------------------
// lossh: gather normalized fp16 rows, dot -> cosines, smooth-L1, per-block
// partial. XCD batch-affinity swizzle (3 MB fp16/batch < 4 MB per-XCD L2).
// ---------------------------------------------------------------------------
__global__ __launch_bounds__(256) void lossh_kernel(const __half* __restrict__ ns,
                                                    const __half* __restrict__ nt,
                                                    const int* __restrict__ idx,
                                                    float* __restrict__ part) {
    const int bid  = blockIdx.x;
    const int v    = (bid & 7) * 512 + (bid >> 3);   // bijective, nwg%8==0
    const int wave = threadIdx.x >> 6;
    const int lane = threadIdx.x & 63;
    const int p    = v * 4 + wave;
    const int base = p & ~(NN - 1);

    int q[8];
    {
        const int4* ip = (const int4*)(idx + (size_t)p * KK);
        int4 a = ip[0], c = ip[1];
        q[0] = base + a.x; q[1] = base + a.y; q[2] = base + a.z; q[3] = base + a.w;
        q[4] = base + c.x; q[5] = base + c.y; q[6] = base + c.z; q[7] = base + c.w;
    }

    const uint2* srow = (const uint2*)(ns + (size_t)p * DD);
    const uint2* trow = (const uint2*)(nt + (size_t)p * DD);
    uint2 sa[3], ta[3];
#pragma unroll
    for (int c = 0; c < 3; ++c) {
        sa[c] = srow[lane + 64 * c];
        ta[c] = trow[lane + 64 * c];
    }

    uint2 sv[8][3], tv[8][3];
#pragma unroll
    for (int j = 0; j < 8; ++j) {
        const uint2* snb = (const uint2*)(ns + (size_t)q[j] * DD);
        const uint2* tnb = (const uint2*)(nt + (size_t)q[j] * DD);
#pragma unroll
        for (int c = 0; c < 3; ++c) {
            sv[j][c] = snb[lane + 64 * c];
            tv[j][c] = tnb[lane + 64 * c];
        }
    }

    float ds[8], dt[8];
#pragma unroll
    for (int j = 0; j < 8; ++j) {
        float a = 0.f, b = 0.f;
#pragma unroll
        for (int c = 0; c < 3; ++c) {
            a = dot4acc(sa[c], sv[j][c], a);
            b = dot4acc(ta[c], tv[j][c], b);
        }
        ds[j] = a;
        dt[j] = b;
    }
#pragma unroll
    for (int m = 1; m < 64; m <<= 1) {
#pragma unroll
        for (int j = 0; j < 8; ++j) {
            ds[j] += __shfl_xor(ds[j], m);
            dt[j] += __shfl_xor(dt[j], m);
        }
    }
    float sum = 0.f;
#pragma unroll
    for (int j = 0; j < 8; ++j) {
        const float diff = fabsf(ds[j] - dt[j]);     // rows pre-normalized
        sum += diff < BETA_F ? (0.5f * diff * diff / BETA_F) : (diff - 0.5f * BETA_F);
    }

    __shared__ float wpart[4];
    if (lane == 0) wpart[wave] = sum;
    __syncthreads();
    if (threadIdx.x == 0)
        part[v] = (wpart[0] + wpart[1]) + (wpart[2] + wpart[3]);
}

// ---------------------------------------------------------------------------
// f32 fallback path (only if ws_size too small for fp16 copies).
// ---------------------------------------------------------------------------
__global__ __launch_bounds__(256) void norm_kernel(const float* __restrict__ s,
                                                   const float* __restrict__ t,
                                                   float* __restrict__ inv_s,
                                                   float* __restrict__ inv_t) {
    const int row  = blockIdx.x * 4 + (threadIdx.x >> 6);
    const int lane = threadIdx.x & 63;
    const float4* srow = (const float4*)(s + (size_t)row * DD);
    const float4* trow = (const float4*)(t + (size_t)row * DD);
    float ss = 0.f, tt = 0.f;
#pragma unroll
    for (int i = 0; i < 3; ++i) {
        float4 v = srow[lane + 64 * i];
        ss = fmaf(v.x, v.x, fmaf(v.y, v.y, fmaf(v.z, v.z, fmaf(v.w, v.w, ss))));
        float4 w = trow[lane + 64 * i];
        tt = fmaf(w.x, w.x, fmaf(w.y, w.y, fmaf(w.z, w.z, fmaf(w.w, w.w, tt))));
    }
#pragma unroll
    for (int m = 1; m < 64; m <<= 1) {
        ss += __shfl_xor(ss, m);
        tt += __shfl_xor(tt, m);
    }
    if (lane == 0) {
        inv_s[row] = 1.0f / fmaxf(sqrtf(ss), EPS_F);
        inv_t[row] = 1.0f / fmaxf(sqrtf(tt), EPS_F);
    }
}

__global__ __launch_bounds__(256) void lossf_kernel(const float* __restrict__ s,
                                                    const float* __restrict__ t,
                                                    const int* __restrict__ idx,
                                                    const float* __restrict__ inv_s,
                                                    const float* __restrict__ inv_t,
                                                    float* __restrict__ part) {
    const int wave = threadIdx.x >> 6;
    const int lane = threadIdx.x & 63;
    const int p    = blockIdx.x * 4 + wave;
    const int base = p & ~(NN - 1);
    int q[8];
    {
        const int4* ip = (const int4*)(idx + (size_t)p * KK);
        int4 a = ip[0], c = ip[1];
        q[0] = base + a.x; q[1] = base + a.y; q[2] = base + a.z; q[3] = base + a.w;
        q[4] = base + c.x; q[5] = base + c.y; q[6] = base + c.z; q[7] = base + c.w;
    }
    float isq[8], itq[8];
#pragma unroll
    for (int j = 0; j < 8; ++j) { isq[j] = inv_s[q[j]]; itq[j] = inv_t[q[j]]; }
    const float isn = inv_s[p];
    const float itn = inv_t[p];
    const float4* srow = (const float4*)(s + (size_t)p * DD);
    const float4* trow = (const float4*)(t + (size_t)p * DD);
    float4 as0 = srow[lane], as1 = srow[lane + 64], as2 = srow[lane + 128];
    float4 at0 = trow[lane], at1 = trow[lane + 64], at2 = trow[lane + 128];
    float ds[8], dt[8];
#pragma unroll
    for (int j = 0; j < 8; ++j) {
        const float4* snb = (const float4*)(s + (size_t)q[j] * DD);
        const float4* tnb = (const float4*)(t + (size_t)q[j] * DD);
        float4 v0 = snb[lane], v1 = snb[lane + 64], v2 = snb[lane + 128];
        float4 w0 = tnb[lane], w1 = tnb[lane + 64], w2 = tnb[lane + 128];
        float a = 0.f, b = 0.f;
        a = fmaf(as0.x, v0.x, a); a = fmaf(as0.y, v0.y, a);
        a = fmaf(as0.z, v0.z, a); a = fmaf(as0.w, v0.w, a);
        a = fmaf(as1.x, v1.x, a); a = fmaf(as1.y, v1.y, a);
        a = fmaf(as1.z, v1.z, a); a = fmaf(as1.w, v1.w, a);
        a = fmaf(as2.x, v2.x, a); a = fmaf(as2.y, v2.y, a);
        a = fmaf(as2.z, v2.z, a); a = fmaf(as2.w, v2.w, a);
        b = fmaf(at0.x, w0.x, b); b = fmaf(at0.y, w0.y, b);
        b = fmaf(at0.z, w0.z, b); b = fmaf(at0.w, w0.w, b);
        b = fmaf(at1.x, w1.x, b); b = fmaf(at1.y, w1.y, b);
        b = fmaf(at1.z, w1.z, b); b = fmaf(at1.w, w1.w, b);
        b = fmaf(at2.x, w2.x, b); b = fmaf(at2.y, w2.y, b);
        b = fmaf(at2.z, w2.z, b); b = fmaf(at2.w, w2.w, b);
        ds[j] = a; dt[j] = b;
    }
#pragma unroll
    for (int m = 1; m < 64; m <<= 1) {
#pragma unroll
        for (int j = 0; j < 8; ++j) {
            ds[j] += __shfl_xor(ds[j], m);
            dt[j] += __shfl_xor(dt[j], m);
        }
    }
    float sum = 0.f;
#pragma unroll
    for (int j = 0; j < 8; ++j) {
        const float cs   = ds[j] * isn * isq[j];
        const float ct   = dt[j] * itn * itq[j];
        const float diff = fabsf(cs - ct);
        sum += diff < BETA_F ? (0.5f * diff * diff / BETA_F) : (diff - 0.5f * BETA_F);
    }
    __shared__ float wpart[4];
    if (lane == 0) wpart[wave] = sum;
    __syncthreads();
    if (threadIdx.x == 0)
        part[blockIdx.x] = (wpart[0] + wpart[1]) + (wpart[2] + wpart[3]);
}

// ---------------------------------------------------------------------------
// finalize: deterministic tree reduce of 4096 block partials + final scale.
// ---------------------------------------------------------------------------
__global__ __launch_bounds__(256) void finalize_kernel(const float* __restrict__ part,
                                                       float* __restrict__ out) {
    __shared__ float red[256];
    float acc = 0.f;
    for (int i = threadIdx.x; i < (BB * NN) / 4; i += 256) acc += part[i];
    red[threadIdx.x] = acc;
    __syncthreads();
    for (int off = 128; off > 0; off >>= 1) {
        if (threadIdx.x < off) red[threadIdx.x] += red[threadIdx.x + off];
        __syncthreads();
    }
    if (threadIdx.x == 0) out[0] = red[0] * (1.0f / (float)(BB * NN * KK));
}

extern "C" void kernel_launch(void* const* d_in, const int* in_sizes, int n_in,
                              void* d_out, int out_size, void* d_ws, size_t ws_size,
                              hipStream_t stream) {
    const float* student = (const float*)d_in[0];
    const float* teacher = (const float*)d_in[1];
    const float* centers = (const float*)d_in[2];
    float* out = (float*)d_out;

    const size_t idx_bytes  = (size_t)BB * NN * KK * sizeof(int);      // 512 KB
    const size_t half_bytes = (size_t)BB * NN * DD * sizeof(__half);   // 25.2 MB
    const size_t part_bytes = 4096 * sizeof(float);
    int* idx_buf = (int*)d_ws;

    if (ws_size >= idx_bytes + 2 * half_bytes + part_bytes) {
        __half* ns  = (__half*)((char*)d_ws + idx_bytes);
        __half* nt  = ns + (size_t)BB * NN * DD;
        float* part = (float*)((char*)d_ws + idx_bytes + 2 * half_bytes);
        fused_prep<<<TPK_BLOCKS + NORM_BLOCKS, 256, 0, stream>>>(centers, student,
                                                                 teacher, idx_buf, ns, nt);
        lossh_kernel<<<NORM_BLOCKS, 256, 0, stream>>>(ns, nt, idx_buf, part);
        finalize_kernel<<<1, 256, 0, stream>>>(part, out);
    } else {
        float* inv_s = (float*)((char*)d_ws + idx_bytes);
        float* inv_t = inv_s + BB * NN;
        float* part  = inv_t + BB * NN;
        topk_kernel<<<TPK_BLOCKS, 256, 0, stream>>>(centers, idx_buf);
        norm_kernel<<<NORM_BLOCKS, 256, 0, stream>>>(student, teacher, inv_s, inv_t);
        lossf_kernel<<<NORM_BLOCKS, 256, 0, stream>>>(student, teacher, idx_buf,
                                                      inv_s, inv_t, part);
        finalize_kernel<<<1, 256, 0, stream>>>(part, out);
    }
}

// Round 7
// 93.649 us; speedup vs baseline: 5.0452x; 1.1276x over previous
//
#include <hip/hip_runtime.h>
#include <hip/hip_fp16.h>
#include <math.h>

#define BB 16
#define NN 1024
#define DD 768
#define KK 8
#define BETA_F 0.5f
#define EPS_F 1e-8f

#define TPK_BLOCKS ((BB * NN) / 4)         // 4096: one wave per point, 4 points/block
#define NORM_BLOCKS ((BB * NN) / 4)        // 4096

typedef _Float16 h2_t __attribute__((ext_vector_type(2)));

#if defined(__has_builtin)
#if __has_builtin(__builtin_amdgcn_fdot2)
#define HAVE_FDOT2 1
#endif
#endif

// acc += dot of 4 halves packed in uint2 (v_dot2_f32_f16 x2, or unpack-fma fallback)
__device__ __forceinline__ float dot4acc(uint2 a, uint2 b, float acc) {
#ifdef HAVE_FDOT2
    acc = __builtin_amdgcn_fdot2(__builtin_bit_cast(h2_t, a.x),
                                 __builtin_bit_cast(h2_t, b.x), acc, false);
    acc = __builtin_amdgcn_fdot2(__builtin_bit_cast(h2_t, a.y),
                                 __builtin_bit_cast(h2_t, b.y), acc, false);
#else
    float2 fa = __half22float2(__builtin_bit_cast(__half2, a.x));
    float2 fb = __half22float2(__builtin_bit_cast(__half2, b.x));
    acc = fmaf(fa.x, fb.x, acc); acc = fmaf(fa.y, fb.y, acc);
    fa = __half22float2(__builtin_bit_cast(__half2, a.y));
    fb = __half22float2(__builtin_bit_cast(__half2, b.y));
    acc = fmaf(fa.x, fb.x, acc); acc = fmaf(fa.y, fb.y, acc);
#endif
    return acc;
}

// ---------------------------------------------------------------------------
// topk: exact top-9 NN per point via wave-wide 9-round min extraction.
// Order key: monotone-uint32(d2) then index — identical total order to all
// prior passing rounds. Key is held as an EXACT f64 integer:
//   key = (double)u * 1024 + m   (u < 2^32, m < 1024  =>  key < 2^42 exact)
// so fmin / == reproduce the (d2, m) lexicographic order bit-exactly.
// One wave per point: lane holds 16 keys (m = 64*i + lane); 9 rounds of
// {butterfly fmin-reduce -> invalidate winner -> local tree recompute}.
// First extracted key is the self/min slot -> dropped (matches idx[:,:,1:]).
// ---------------------------------------------------------------------------
__device__ __forceinline__ unsigned topk_u(float anx, float any_, float sqn, float4 c) {
    float dot = anx * c.x + any_ * c.y;
    float d2  = (sqn + c.z) - 2.0f * dot;
    unsigned int u = __float_as_uint(d2);
    u ^= (unsigned int)((int)u >> 31) | 0x80000000u;
    return u;
}

#define KINF 1.0e300

#define K16(X) X(0) X(1) X(2) X(3) X(4) X(5) X(6) X(7) \
               X(8) X(9) X(10) X(11) X(12) X(13) X(14) X(15)

#define MINTREE() fmin(fmin(fmin(fmin(k0,k1),fmin(k2,k3)),                 \
                            fmin(fmin(k4,k5),fmin(k6,k7))),               \
                       fmin(fmin(fmin(k8,k9),fmin(k10,k11)),              \
                            fmin(fmin(k12,k13),fmin(k14,k15))))

__device__ __forceinline__ void topk_wave_body(const float* __restrict__ centers,
                                               int* __restrict__ idx_out,
                                               int tb, int tid, float4* c4) {
    const int b    = tb >> 8;          // 256 blocks per batch
    const int grp  = tb & 255;
    const int wave = tid >> 6;
    const int lane = tid & 63;

    // stage packed (x, y, x^2+y^2) — identical arithmetic to prior rounds
    const float4* cbase = (const float4*)(centers + (size_t)b * NN * 2);
    for (int i = tid; i < NN / 2; i += 256) {
        float4 v = cbase[i];
        c4[2 * i + 0] = make_float4(v.x, v.y, v.x * v.x + v.y * v.y, 0.f);
        c4[2 * i + 1] = make_float4(v.z, v.w, v.z * v.z + v.w * v.w, 0.f);
    }
    __syncthreads();

    const int    n   = grp * 4 + wave;   // point within batch
    const float4 cn  = c4[n];
    const float  anx = cn.x, any_ = cn.y, sqn = cn.z;

#define DK(i) double k##i;
    K16(DK)
#undef DK
#define IK(i) { const int m_ = (i) * 64 + lane;                            \
                float4 c_ = c4[m_];                                        \
                unsigned u_ = topk_u(anx, any_, sqn, c_);                  \
                k##i = fma((double)u_, 1024.0, (double)m_); }
    K16(IK)
#undef IK

    double lm = MINTREE();
    int mm[9];

#define VK(i) k##i = (k##i == g) ? KINF : k##i;
#define TOPK_ROUND(r) {                                                    \
        double g = lm;                                                     \
        g = fmin(g, __shfl_xor(g, 1));                                     \
        g = fmin(g, __shfl_xor(g, 2));                                     \
        g = fmin(g, __shfl_xor(g, 4));                                     \
        g = fmin(g, __shfl_xor(g, 8));                                     \
        g = fmin(g, __shfl_xor(g, 16));                                    \
        g = fmin(g, __shfl_xor(g, 32));                                    \
        double qf = floor(g * 0.0009765625) * 1024.0;                      \
        mm[r] = (int)(g - qf);                                             \
        K16(VK)                                                            \
        lm = MINTREE();                                                    \
    }
    TOPK_ROUND(0)   // self / global min — dropped below
    TOPK_ROUND(1)
    TOPK_ROUND(2)
    TOPK_ROUND(3)
    TOPK_ROUND(4)
    TOPK_ROUND(5)
    TOPK_ROUND(6)
    TOPK_ROUND(7)
    TOPK_ROUND(8)
#undef TOPK_ROUND
#undef VK

    if (lane == 0) {
        int* outp = idx_out + ((size_t)b * NN + n) * KK;
        ((int4*)outp)[0] = make_int4(mm[1], mm[2], mm[3], mm[4]);
        ((int4*)outp)[1] = make_int4(mm[5], mm[6], mm[7], mm[8]);
    }
}

// ---------------------------------------------------------------------------
// normh body: row-normalize s,t in fp32, emit normalized fp16. One wave/row.
// (unchanged from round 6)
// ---------------------------------------------------------------------------
__device__ __forceinline__ void normh_body(const float* __restrict__ s,
                                           const float* __restrict__ t,
                                           __half* __restrict__ ns,
                                           __half* __restrict__ nt,
                                           int nb, int tid) {
    const int row  = nb * 4 + (tid >> 6);
    const int lane = tid & 63;
    const float4* srow = (const float4*)(s + (size_t)row * DD);
    const float4* trow = (const float4*)(t + (size_t)row * DD);
    float4 vs[3], vt[3];
    float ss = 0.f, tt = 0.f;
#pragma unroll
    for (int i = 0; i < 3; ++i) {
        vs[i] = srow[lane + 64 * i];
        vt[i] = trow[lane + 64 * i];
        ss = fmaf(vs[i].x, vs[i].x, fmaf(vs[i].y, vs[i].y,
             fmaf(vs[i].z, vs[i].z, fmaf(vs[i].w, vs[i].w, ss))));
        tt = fmaf(vt[i].x, vt[i].x, fmaf(vt[i].y, vt[i].y,
             fmaf(vt[i].z, vt[i].z, fmaf(vt[i].w, vt[i].w, tt))));
    }
#pragma unroll
    for (int m = 1; m < 64; m <<= 1) {
        ss += __shfl_xor(ss, m);
        tt += __shfl_xor(tt, m);
    }
    const float is_ = 1.0f / fmaxf(sqrtf(ss), EPS_F);
    const float it_ = 1.0f / fmaxf(sqrtf(tt), EPS_F);

    uint2* nsrow = (uint2*)(ns + (size_t)row * DD);
    uint2* ntrow = (uint2*)(nt + (size_t)row * DD);
#pragma unroll
    for (int i = 0; i < 3; ++i) {
        __half2 a0 = __floats2half2_rn(vs[i].x * is_, vs[i].y * is_);
        __half2 a1 = __floats2half2_rn(vs[i].z * is_, vs[i].w * is_);
        __half2 b0 = __floats2half2_rn(vt[i].x * it_, vt[i].y * it_);
        __half2 b1 = __floats2half2_rn(vt[i].z * it_, vt[i].w * it_);
        uint2 ua; ua.x = __builtin_bit_cast(unsigned int, a0);
        ua.y = __builtin_bit_cast(unsigned int, a1);
        uint2 ub; ub.x = __builtin_bit_cast(unsigned int, b0);
        ub.y = __builtin_bit_cast(unsigned int, b1);
        nsrow[lane + 64 * i] = ua;
        ntrow[lane + 64 * i] = ub;
    }
}

// ---------------------------------------------------------------------------
// Fused kernel: roles interleaved on blockIdx&1 so every CU overlaps the
// VALU-bound topk with the HBM-bound normh from t=0. LDS is only 16 KB now
// -> 8 blocks/CU (the wave cap), so normh keeps full streaming occupancy.
// ---------------------------------------------------------------------------
__global__ __launch_bounds__(256) void fused_prep(const float* __restrict__ centers,
                                                  const float* __restrict__ s,
                                                  const float* __restrict__ t,
                                                  int* __restrict__ idx_out,
                                                  __half* __restrict__ ns,
                                                  __half* __restrict__ nt) {
    __shared__ float4 c4[NN];                 // 16 KB
    const int role = blockIdx.x & 1;
    const int tb   = blockIdx.x >> 1;
    if (role == 0)
        topk_wave_body(centers, idx_out, tb, threadIdx.x, c4);
    else
        normh_body(s, t, ns, nt, tb, threadIdx.x);
}

// standalone topk for the f32 fallback path
__global__ __launch_bounds__(256) void topk_kernel(const float* __restrict__ centers,
                                                   int* __restrict__ idx_out) {
    __shared__ float4 c4[NN];
    topk_wave_body(centers, idx_out, blockIdx.x, threadIdx.x, c4);
}

// ---------------------------------------------------------------------------
// lossh: gather normalized fp16 rows, dot -> cosines, smooth-L1, per-block
// partial. XCD batch-affinity swizzle. (unchanged from round 6)
// ---------------------------------------------------------------------------
__global__ __launch_bounds__(256) void lossh_kernel(const __half* __restrict__ ns,
                                                    const __half* __restrict__ nt,
                                                    const int* __restrict__ idx,
                                                    float* __restrict__ part) {
    const int bid  = blockIdx.x;
    const int v    = (bid & 7) * 512 + (bid >> 3);   // bijective, nwg%8==0
    const int wave = threadIdx.x >> 6;
    const int lane = threadIdx.x & 63;
    const int p    = v * 4 + wave;
    const int base = p & ~(NN - 1);

    int q[8];
    {
        const int4* ip = (const int4*)(idx + (size_t)p * KK);
        int4 a = ip[0], c = ip[1];
        q[0] = base + a.x; q[1] = base + a.y; q[2] = base + a.z; q[3] = base + a.w;
        q[4] = base + c.x; q[5] = base + c.y; q[6] = base + c.z; q[7] = base + c.w;
    }

    const uint2* srow = (const uint2*)(ns + (size_t)p * DD);
    const uint2* trow = (const uint2*)(nt + (size_t)p * DD);
    uint2 sa[3], ta[3];
#pragma unroll
    for (int c = 0; c < 3; ++c) {
        sa[c] = srow[lane + 64 * c];
        ta[c] = trow[lane + 64 * c];
    }

    uint2 sv[8][3], tv[8][3];
#pragma unroll
    for (int j = 0; j < 8; ++j) {
        const uint2* snb = (const uint2*)(ns + (size_t)q[j] * DD);
        const uint2* tnb = (const uint2*)(nt + (size_t)q[j] * DD);
#pragma unroll
        for (int c = 0; c < 3; ++c) {
            sv[j][c] = snb[lane + 64 * c];
            tv[j][c] = tnb[lane + 64 * c];
        }
    }

    float ds[8], dt[8];
#pragma unroll
    for (int j = 0; j < 8; ++j) {
        float a = 0.f, b = 0.f;
#pragma unroll
        for (int c = 0; c < 3; ++c) {
            a = dot4acc(sa[c], sv[j][c], a);
            b = dot4acc(ta[c], tv[j][c], b);
        }
        ds[j] = a;
        dt[j] = b;
    }
#pragma unroll
    for (int m = 1; m < 64; m <<= 1) {
#pragma unroll
        for (int j = 0; j < 8; ++j) {
            ds[j] += __shfl_xor(ds[j], m);
            dt[j] += __shfl_xor(dt[j], m);
        }
    }
    float sum = 0.f;
#pragma unroll
    for (int j = 0; j < 8; ++j) {
        const float diff = fabsf(ds[j] - dt[j]);     // rows pre-normalized
        sum += diff < BETA_F ? (0.5f * diff * diff / BETA_F) : (diff - 0.5f * BETA_F);
    }

    __shared__ float wpart[4];
    if (lane == 0) wpart[wave] = sum;
    __syncthreads();
    if (threadIdx.x == 0)
        part[v] = (wpart[0] + wpart[1]) + (wpart[2] + wpart[3]);
}

// ---------------------------------------------------------------------------
// f32 fallback path (only if ws_size too small for fp16 copies).
// ---------------------------------------------------------------------------
__global__ __launch_bounds__(256) void norm_kernel(const float* __restrict__ s,
                                                   const float* __restrict__ t,
                                                   float* __restrict__ inv_s,
                                                   float* __restrict__ inv_t) {
    const int row  = blockIdx.x * 4 + (threadIdx.x >> 6);
    const int lane = threadIdx.x & 63;
    const float4* srow = (const float4*)(s + (size_t)row * DD);
    const float4* trow = (const float4*)(t + (size_t)row * DD);
    float ss = 0.f, tt = 0.f;
#pragma unroll
    for (int i = 0; i < 3; ++i) {
        float4 v = srow[lane + 64 * i];
        ss = fmaf(v.x, v.x, fmaf(v.y, v.y, fmaf(v.z, v.z, fmaf(v.w, v.w, ss))));
        float4 w = trow[lane + 64 * i];
        tt = fmaf(w.x, w.x, fmaf(w.y, w.y, fmaf(w.z, w.z, fmaf(w.w, w.w, tt))));
    }
#pragma unroll
    for (int m = 1; m < 64; m <<= 1) {
        ss += __shfl_xor(ss, m);
        tt += __shfl_xor(tt, m);
    }
    if (lane == 0) {
        inv_s[row] = 1.0f / fmaxf(sqrtf(ss), EPS_F);
        inv_t[row] = 1.0f / fmaxf(sqrtf(tt), EPS_F);
    }
}

__global__ __launch_bounds__(256) void lossf_kernel(const float* __restrict__ s,
                                                    const float* __restrict__ t,
                                                    const int* __restrict__ idx,
                                                    const float* __restrict__ inv_s,
                                                    const float* __restrict__ inv_t,
                                                    float* __restrict__ part) {
    const int wave = threadIdx.x >> 6;
    const int lane = threadIdx.x & 63;
    const int p    = blockIdx.x * 4 + wave;
    const int base = p & ~(NN - 1);
    int q[8];
    {
        const int4* ip = (const int4*)(idx + (size_t)p * KK);
        int4 a = ip[0], c = ip[1];
        q[0] = base + a.x; q[1] = base + a.y; q[2] = base + a.z; q[3] = base + a.w;
        q[4] = base + c.x; q[5] = base + c.y; q[6] = base + c.z; q[7] = base + c.w;
    }
    float isq[8], itq[8];
#pragma unroll
    for (int j = 0; j < 8; ++j) { isq[j] = inv_s[q[j]]; itq[j] = inv_t[q[j]]; }
    const float isn = inv_s[p];
    const float itn = inv_t[p];
    const float4* srow = (const float4*)(s + (size_t)p * DD);
    const float4* trow = (const float4*)(t + (size_t)p * DD);
    float4 as0 = srow[lane], as1 = srow[lane + 64], as2 = srow[lane + 128];
    float4 at0 = trow[lane], at1 = trow[lane + 64], at2 = trow[lane + 128];
    float ds[8], dt[8];
#pragma unroll
    for (int j = 0; j < 8; ++j) {
        const float4* snb = (const float4*)(s + (size_t)q[j] * DD);
        const float4* tnb = (const float4*)(t + (size_t)q[j] * DD);
        float4 v0 = snb[lane], v1 = snb[lane + 64], v2 = snb[lane + 128];
        float4 w0 = tnb[lane], w1 = tnb[lane + 64], w2 = tnb[lane + 128];
        float a = 0.f, b = 0.f;
        a = fmaf(as0.x, v0.x, a); a = fmaf(as0.y, v0.y, a);
        a = fmaf(as0.z, v0.z, a); a = fmaf(as0.w, v0.w, a);
        a = fmaf(as1.x, v1.x, a); a = fmaf(as1.y, v1.y, a);
        a = fmaf(as1.z, v1.z, a); a = fmaf(as1.w, v1.w, a);
        a = fmaf(as2.x, v2.x, a); a = fmaf(as2.y, v2.y, a);
        a = fmaf(as2.z, v2.z, a); a = fmaf(as2.w, v2.w, a);
        b = fmaf(at0.x, w0.x, b); b = fmaf(at0.y, w0.y, b);
        b = fmaf(at0.z, w0.z, b); b = fmaf(at0.w, w0.w, b);
        b = fmaf(at1.x, w1.x, b); b = fmaf(at1.y, w1.y, b);
        b = fmaf(at1.z, w1.z, b); b = fmaf(at1.w, w1.w, b);
        b = fmaf(at2.x, w2.x, b); b = fmaf(at2.y, w2.y, b);
        b = fmaf(at2.z, w2.z, b); b = fmaf(at2.w, w2.w, b);
        ds[j] = a; dt[j] = b;
    }
#pragma unroll
    for (int m = 1; m < 64; m <<= 1) {
#pragma unroll
        for (int j = 0; j < 8; ++j) {
            ds[j] += __shfl_xor(ds[j], m);
            dt[j] += __shfl_xor(dt[j], m);
        }
    }
    float sum = 0.f;
#pragma unroll
    for (int j = 0; j < 8; ++j) {
        const float cs   = ds[j] * isn * isq[j];
        const float ct   = dt[j] * itn * itq[j];
        const float diff = fabsf(cs - ct);
        sum += diff < BETA_F ? (0.5f * diff * diff / BETA_F) : (diff - 0.5f * BETA_F);
    }
    __shared__ float wpart[4];
    if (lane == 0) wpart[wave] = sum;
    __syncthreads();
    if (threadIdx.x == 0)
        part[blockIdx.x] = (wpart[0] + wpart[1]) + (wpart[2] + wpart[3]);
}

// ---------------------------------------------------------------------------
// finalize: deterministic tree reduce of 4096 block partials + final scale.
// ---------------------------------------------------------------------------
__global__ __launch_bounds__(256) void finalize_kernel(const float* __restrict__ part,
                                                       float* __restrict__ out) {
    __shared__ float red[256];
    float acc = 0.f;
    for (int i = threadIdx.x; i < (BB * NN) / 4; i += 256) acc += part[i];
    red[threadIdx.x] = acc;
    __syncthreads();
    for (int off = 128; off > 0; off >>= 1) {
        if (threadIdx.x < off) red[threadIdx.x] += red[threadIdx.x + off];
        __syncthreads();
    }
    if (threadIdx.x == 0) out[0] = red[0] * (1.0f / (float)(BB * NN * KK));
}

extern "C" void kernel_launch(void* const* d_in, const int* in_sizes, int n_in,
                              void* d_out, int out_size, void* d_ws, size_t ws_size,
                              hipStream_t stream) {
    const float* student = (const float*)d_in[0];
    const float* teacher = (const float*)d_in[1];
    const float* centers = (const float*)d_in[2];
    float* out = (float*)d_out;

    const size_t idx_bytes  = (size_t)BB * NN * KK * sizeof(int);      // 512 KB
    const size_t half_bytes = (size_t)BB * NN * DD * sizeof(__half);   // 25.2 MB
    const size_t part_bytes = 4096 * sizeof(float);
    int* idx_buf = (int*)d_ws;

    if (ws_size >= idx_bytes + 2 * half_bytes + part_bytes) {
        __half* ns  = (__half*)((char*)d_ws + idx_bytes);
        __half* nt  = ns + (size_t)BB * NN * DD;
        float* part = (float*)((char*)d_ws + idx_bytes + 2 * half_bytes);
        fused_prep<<<TPK_BLOCKS + NORM_BLOCKS, 256, 0, stream>>>(centers, student,
                                                                 teacher, idx_buf, ns, nt);
        lossh_kernel<<<NORM_BLOCKS, 256, 0, stream>>>(ns, nt, idx_buf, part);
        finalize_kernel<<<1, 256, 0, stream>>>(part, out);
    } else {
        float* inv_s = (float*)((char*)d_ws + idx_bytes);
        float* inv_t = inv_s + BB * NN;
        float* part  = inv_t + BB * NN;
        topk_kernel<<<TPK_BLOCKS, 256, 0, stream>>>(centers, idx_buf);
        norm_kernel<<<NORM_BLOCKS, 256, 0, stream>>>(student, teacher, inv_s, inv_t);
        lossf_kernel<<<NORM_BLOCKS, 256, 0, stream>>>(student, teacher, idx_buf,
                                                      inv_s, inv_t, part);
        finalize_kernel<<<1, 256, 0, stream>>>(part, out);
    }
}

// Round 8
// 93.337 us; speedup vs baseline: 5.0621x; 1.0033x over previous
//
#include <hip/hip_runtime.h>
#include <hip/hip_fp16.h>
#include <math.h>

#define BB 16
#define NN 1024
#define DD 768
#define KK 8
#define BETA_F 0.5f
#define EPS_F 1e-8f

#define TPK_BLOCKS ((BB * NN) / 4)         // 4096: one wave per point, 4 points/block
#define NORM_BLOCKS ((BB * NN) / 4)        // 4096

typedef _Float16 h2_t __attribute__((ext_vector_type(2)));

#if defined(__has_builtin)
#if __has_builtin(__builtin_amdgcn_fdot2)
#define HAVE_FDOT2 1
#endif
#endif

// acc += dot of 4 halves packed in uint2 (v_dot2_f32_f16 x2, or unpack-fma fallback)
__device__ __forceinline__ float dot4acc(uint2 a, uint2 b, float acc) {
#ifdef HAVE_FDOT2
    acc = __builtin_amdgcn_fdot2(__builtin_bit_cast(h2_t, a.x),
                                 __builtin_bit_cast(h2_t, b.x), acc, false);
    acc = __builtin_amdgcn_fdot2(__builtin_bit_cast(h2_t, a.y),
                                 __builtin_bit_cast(h2_t, b.y), acc, false);
#else
    float2 fa = __half22float2(__builtin_bit_cast(__half2, a.x));
    float2 fb = __half22float2(__builtin_bit_cast(__half2, b.x));
    acc = fmaf(fa.x, fb.x, acc); acc = fmaf(fa.y, fb.y, acc);
    fa = __half22float2(__builtin_bit_cast(__half2, a.y));
    fb = __half22float2(__builtin_bit_cast(__half2, b.y));
    acc = fmaf(fa.x, fb.x, acc); acc = fmaf(fa.y, fb.y, acc);
#endif
    return acc;
}

// ---------------------------------------------------------------------------
// topk: exact top-9 NN per point, wave-wide 9-round min extraction with a
// REGISTER TOURNAMENT TREE. Key = (double)u * 1024 + m (exact integer < 2^42,
// same arithmetic as rounds 6-7, proven bit-exact vs jax top_k).
// Extracted key gm = i*64 + lane_w encodes its own location: the leaf index
// j = gm>>6 is WAVE-UNIFORM -> readfirstlane + scalar switch updates only the
// 4-node path (5 fmins) instead of a 16-cmp invalidate scan + 15-fmin rebuild.
// ---------------------------------------------------------------------------
__device__ __forceinline__ unsigned topk_u(float anx, float any_, float sqn, float4 c) {
    float dot = anx * c.x + any_ * c.y;
    float d2  = (sqn + c.z) - 2.0f * dot;
    unsigned int u = __float_as_uint(d2);
    u ^= (unsigned int)((int)u >> 31) | 0x80000000u;
    return u;
}

#define KINF 1.0e300

#define K16(X) X(0) X(1) X(2) X(3) X(4) X(5) X(6) X(7) \
               X(8) X(9) X(10) X(11) X(12) X(13) X(14) X(15)

// case J: kill leaf J on the winning lane, recompute its tree path.
#define TOPK_CASE(J, L0, L1, AN, A0, A1, BN, B0, B1, CN)                   \
    case J:                                                                \
        k##J = win ? kinf : k##J;                                          \
        AN = fmin(L0, L1);                                                 \
        BN = fmin(A0, A1);                                                 \
        CN = fmin(B0, B1);                                                 \
        troot = fmin(nc0, nc1);                                            \
        break;

#define TOPK_SWITCH                                                        \
    switch (j) {                                                           \
        TOPK_CASE(0,  k0,  k1,  na0, na0, na1, nb0, nb0, nb1, nc0)        \
        TOPK_CASE(1,  k0,  k1,  na0, na0, na1, nb0, nb0, nb1, nc0)        \
        TOPK_CASE(2,  k2,  k3,  na1, na0, na1, nb0, nb0, nb1, nc0)        \
        TOPK_CASE(3,  k2,  k3,  na1, na0, na1, nb0, nb0, nb1, nc0)        \
        TOPK_CASE(4,  k4,  k5,  na2, na2, na3, nb1, nb0, nb1, nc0)        \
        TOPK_CASE(5,  k4,  k5,  na2, na2, na3, nb1, nb0, nb1, nc0)        \
        TOPK_CASE(6,  k6,  k7,  na3, na2, na3, nb1, nb0, nb1, nc0)        \
        TOPK_CASE(7,  k6,  k7,  na3, na2, na3, nb1, nb0, nb1, nc0)        \
        TOPK_CASE(8,  k8,  k9,  na4, na4, na5, nb2, nb2, nb3, nc1)        \
        TOPK_CASE(9,  k8,  k9,  na4, na4, na5, nb2, nb2, nb3, nc1)        \
        TOPK_CASE(10, k10, k11, na5, na4, na5, nb2, nb2, nb3, nc1)        \
        TOPK_CASE(11, k10, k11, na5, na4, na5, nb2, nb2, nb3, nc1)        \
        TOPK_CASE(12, k12, k13, na6, na6, na7, nb3, nb2, nb3, nc1)        \
        TOPK_CASE(13, k12, k13, na6, na6, na7, nb3, nb2, nb3, nc1)        \
        TOPK_CASE(14, k14, k15, na7, na6, na7, nb3, nb2, nb3, nc1)        \
        TOPK_CASE(15, k14, k15, na7, na6, na7, nb3, nb2, nb3, nc1)        \
    }

__device__ __forceinline__ void topk_wave_body(const float* __restrict__ centers,
                                               int* __restrict__ idx_out,
                                               int tb, int tid, float4* c4) {
    const int b    = tb >> 8;          // 256 blocks per batch
    const int grp  = tb & 255;
    const int wave = tid >> 6;
    const int lane = tid & 63;

    // stage packed (x, y, x^2+y^2) — identical arithmetic to prior rounds
    const float4* cbase = (const float4*)(centers + (size_t)b * NN * 2);
    for (int i = tid; i < NN / 2; i += 256) {
        float4 v = cbase[i];
        c4[2 * i + 0] = make_float4(v.x, v.y, v.x * v.x + v.y * v.y, 0.f);
        c4[2 * i + 1] = make_float4(v.z, v.w, v.z * v.z + v.w * v.w, 0.f);
    }
    __syncthreads();

    const int    n   = grp * 4 + wave;   // point within batch
    const float4 cn  = c4[n];
    const float  anx = cn.x, any_ = cn.y, sqn = cn.z;
    const double kinf = KINF;

#define DK(i) double k##i;
    K16(DK)
#undef DK
#define IK(i) { const int m_ = (i) * 64 + lane;                            \
                float4 c_ = c4[m_];                                        \
                unsigned u_ = topk_u(anx, any_, sqn, c_);                  \
                k##i = fma((double)u_, 1024.0, (double)m_); }
    K16(IK)
#undef IK

    // tournament tree (all keys distinct: m is unique per (i,lane))
    double na0 = fmin(k0, k1),   na1 = fmin(k2, k3);
    double na2 = fmin(k4, k5),   na3 = fmin(k6, k7);
    double na4 = fmin(k8, k9),   na5 = fmin(k10, k11);
    double na6 = fmin(k12, k13), na7 = fmin(k14, k15);
    double nb0 = fmin(na0, na1), nb1 = fmin(na2, na3);
    double nb2 = fmin(na4, na5), nb3 = fmin(na6, na7);
    double nc0 = fmin(nb0, nb1), nc1 = fmin(nb2, nb3);
    double troot = fmin(nc0, nc1);

    int mm[9];

#define TOPK_ROUND(r) {                                                    \
        double g = troot;                                                  \
        g = fmin(g, __shfl_xor(g, 1));                                     \
        g = fmin(g, __shfl_xor(g, 2));                                     \
        g = fmin(g, __shfl_xor(g, 4));                                     \
        g = fmin(g, __shfl_xor(g, 8));                                     \
        g = fmin(g, __shfl_xor(g, 16));                                    \
        g = fmin(g, __shfl_xor(g, 32));                                    \
        double qf = floor(g * 0.0009765625) * 1024.0;                      \
        const int gm = (int)(g - qf);                                      \
        mm[r] = gm;                                                        \
        const int j = __builtin_amdgcn_readfirstlane(gm >> 6);             \
        const bool win = (gm & 63) == lane;                                \
        TOPK_SWITCH                                                        \
    }
    TOPK_ROUND(0)   // global min (self or negative-rounded pair) — dropped
    TOPK_ROUND(1)
    TOPK_ROUND(2)
    TOPK_ROUND(3)
    TOPK_ROUND(4)
    TOPK_ROUND(5)
    TOPK_ROUND(6)
    TOPK_ROUND(7)
    TOPK_ROUND(8)
#undef TOPK_ROUND

    if (lane == 0) {
        int* outp = idx_out + ((size_t)b * NN + n) * KK;
        ((int4*)outp)[0] = make_int4(mm[1], mm[2], mm[3], mm[4]);
        ((int4*)outp)[1] = make_int4(mm[5], mm[6], mm[7], mm[8]);
    }
}

// ---------------------------------------------------------------------------
// normh body: row-normalize s,t in fp32, emit normalized fp16. One wave/row.
// (unchanged from rounds 6-7)
// ---------------------------------------------------------------------------
__device__ __forceinline__ void normh_body(const float* __restrict__ s,
                                           const float* __restrict__ t,
                                           __half* __restrict__ ns,
                                           __half* __restrict__ nt,
                                           int nb, int tid) {
    const int row  = nb * 4 + (tid >> 6);
    const int lane = tid & 63;
    const float4* srow = (const float4*)(s + (size_t)row * DD);
    const float4* trow = (const float4*)(t + (size_t)row * DD);
    float4 vs[3], vt[3];
    float ss = 0.f, tt = 0.f;
#pragma unroll
    for (int i = 0; i < 3; ++i) {
        vs[i] = srow[lane + 64 * i];
        vt[i] = trow[lane + 64 * i];
        ss = fmaf(vs[i].x, vs[i].x, fmaf(vs[i].y, vs[i].y,
             fmaf(vs[i].z, vs[i].z, fmaf(vs[i].w, vs[i].w, ss))));
        tt = fmaf(vt[i].x, vt[i].x, fmaf(vt[i].y, vt[i].y,
             fmaf(vt[i].z, vt[i].z, fmaf(vt[i].w, vt[i].w, tt))));
    }
#pragma unroll
    for (int m = 1; m < 64; m <<= 1) {
        ss += __shfl_xor(ss, m);
        tt += __shfl_xor(tt, m);
    }
    const float is_ = 1.0f / fmaxf(sqrtf(ss), EPS_F);
    const float it_ = 1.0f / fmaxf(sqrtf(tt), EPS_F);

    uint2* nsrow = (uint2*)(ns + (size_t)row * DD);
    uint2* ntrow = (uint2*)(nt + (size_t)row * DD);
#pragma unroll
    for (int i = 0; i < 3; ++i) {
        __half2 a0 = __floats2half2_rn(vs[i].x * is_, vs[i].y * is_);
        __half2 a1 = __floats2half2_rn(vs[i].z * is_, vs[i].w * is_);
        __half2 b0 = __floats2half2_rn(vt[i].x * it_, vt[i].y * it_);
        __half2 b1 = __floats2half2_rn(vt[i].z * it_, vt[i].w * it_);
        uint2 ua; ua.x = __builtin_bit_cast(unsigned int, a0);
        ua.y = __builtin_bit_cast(unsigned int, a1);
        uint2 ub; ub.x = __builtin_bit_cast(unsigned int, b0);
        ub.y = __builtin_bit_cast(unsigned int, b1);
        nsrow[lane + 64 * i] = ua;
        ntrow[lane + 64 * i] = ub;
    }
}

// ---------------------------------------------------------------------------
// Fused kernel: roles interleaved on blockIdx&1 so every CU overlaps the
// VALU-bound topk with the HBM-bound normh from t=0. LDS 16 KB.
// ---------------------------------------------------------------------------
__global__ __launch_bounds__(256) void fused_prep(const float* __restrict__ centers,
                                                  const float* __restrict__ s,
                                                  const float* __restrict__ t,
                                                  int* __restrict__ idx_out,
                                                  __half* __restrict__ ns,
                                                  __half* __restrict__ nt) {
    __shared__ float4 c4[NN];                 // 16 KB
    const int role = blockIdx.x & 1;
    const int tb   = blockIdx.x >> 1;
    if (role == 0)
        topk_wave_body(centers, idx_out, tb, threadIdx.x, c4);
    else
        normh_body(s, t, ns, nt, tb, threadIdx.x);
}

// standalone topk for the f32 fallback path
__global__ __launch_bounds__(256) void topk_kernel(const float* __restrict__ centers,
                                                   int* __restrict__ idx_out) {
    __shared__ float4 c4[NN];
    topk_wave_body(centers, idx_out, blockIdx.x, threadIdx.x, c4);
}

// ---------------------------------------------------------------------------
// lossh: gather normalized fp16 rows, dot -> cosines, smooth-L1, per-block
// partial. XCD batch-affinity swizzle. (unchanged from rounds 6-7)
// ---------------------------------------------------------------------------
__global__ __launch_bounds__(256) void lossh_kernel(const __half* __restrict__ ns,
                                                    const __half* __restrict__ nt,
                                                    const int* __restrict__ idx,
                                                    float* __restrict__ part) {
    const int bid  = blockIdx.x;
    const int v    = (bid & 7) * 512 + (bid >> 3);   // bijective, nwg%8==0
    const int wave = threadIdx.x >> 6;
    const int lane = threadIdx.x & 63;
    const int p    = v * 4 + wave;
    const int base = p & ~(NN - 1);

    int q[8];
    {
        const int4* ip = (const int4*)(idx + (size_t)p * KK);
        int4 a = ip[0], c = ip[1];
        q[0] = base + a.x; q[1] = base + a.y; q[2] = base + a.z; q[3] = base + a.w;
        q[4] = base + c.x; q[5] = base + c.y; q[6] = base + c.z; q[7] = base + c.w;
    }

    const uint2* srow = (const uint2*)(ns + (size_t)p * DD);
    const uint2* trow = (const uint2*)(nt + (size_t)p * DD);
    uint2 sa[3], ta[3];
#pragma unroll
    for (int c = 0; c < 3; ++c) {
        sa[c] = srow[lane + 64 * c];
        ta[c] = trow[lane + 64 * c];
    }

    uint2 sv[8][3], tv[8][3];
#pragma unroll
    for (int j = 0; j < 8; ++j) {
        const uint2* snb = (const uint2*)(ns + (size_t)q[j] * DD);
        const uint2* tnb = (const uint2*)(nt + (size_t)q[j] * DD);
#pragma unroll
        for (int c = 0; c < 3; ++c) {
            sv[j][c] = snb[lane + 64 * c];
            tv[j][c] = tnb[lane + 64 * c];
        }
    }

    float ds[8], dt[8];
#pragma unroll
    for (int j = 0; j < 8; ++j) {
        float a = 0.f, b = 0.f;
#pragma unroll
        for (int c = 0; c < 3; ++c) {
            a = dot4acc(sa[c], sv[j][c], a);
            b = dot4acc(ta[c], tv[j][c], b);
        }
        ds[j] = a;
        dt[j] = b;
    }
#pragma unroll
    for (int m = 1; m < 64; m <<= 1) {
#pragma unroll
        for (int j = 0; j < 8; ++j) {
            ds[j] += __shfl_xor(ds[j], m);
            dt[j] += __shfl_xor(dt[j], m);
        }
    }
    float sum = 0.f;
#pragma unroll
    for (int j = 0; j < 8; ++j) {
        const float diff = fabsf(ds[j] - dt[j]);     // rows pre-normalized
        sum += diff < BETA_F ? (0.5f * diff * diff / BETA_F) : (diff - 0.5f * BETA_F);
    }

    __shared__ float wpart[4];
    if (lane == 0) wpart[wave] = sum;
    __syncthreads();
    if (threadIdx.x == 0)
        part[v] = (wpart[0] + wpart[1]) + (wpart[2] + wpart[3]);
}

// ---------------------------------------------------------------------------
// f32 fallback path (only if ws_size too small for fp16 copies).
// ---------------------------------------------------------------------------
__global__ __launch_bounds__(256) void norm_kernel(const float* __restrict__ s,
                                                   const float* __restrict__ t,
                                                   float* __restrict__ inv_s,
                                                   float* __restrict__ inv_t) {
    const int row  = blockIdx.x * 4 + (threadIdx.x >> 6);
    const int lane = threadIdx.x & 63;
    const float4* srow = (const float4*)(s + (size_t)row * DD);
    const float4* trow = (const float4*)(t + (size_t)row * DD);
    float ss = 0.f, tt = 0.f;
#pragma unroll
    for (int i = 0; i < 3; ++i) {
        float4 v = srow[lane + 64 * i];
        ss = fmaf(v.x, v.x, fmaf(v.y, v.y, fmaf(v.z, v.z, fmaf(v.w, v.w, ss))));
        float4 w = trow[lane + 64 * i];
        tt = fmaf(w.x, w.x, fmaf(w.y, w.y, fmaf(w.z, w.z, fmaf(w.w, w.w, tt))));
    }
#pragma unroll
    for (int m = 1; m < 64; m <<= 1) {
        ss += __shfl_xor(ss, m);
        tt += __shfl_xor(tt, m);
    }
    if (lane == 0) {
        inv_s[row] = 1.0f / fmaxf(sqrtf(ss), EPS_F);
        inv_t[row] = 1.0f / fmaxf(sqrtf(tt), EPS_F);
    }
}

__global__ __launch_bounds__(256) void lossf_kernel(const float* __restrict__ s,
                                                    const float* __restrict__ t,
                                                    const int* __restrict__ idx,
                                                    const float* __restrict__ inv_s,
                                                    const float* __restrict__ inv_t,
                                                    float* __restrict__ part) {
    const int wave = threadIdx.x >> 6;
    const int lane = threadIdx.x & 63;
    const int p    = blockIdx.x * 4 + wave;
    const int base = p & ~(NN - 1);
    int q[8];
    {
        const int4* ip = (const int4*)(idx + (size_t)p * KK);
        int4 a = ip[0], c = ip[1];
        q[0] = base + a.x; q[1] = base + a.y; q[2] = base + a.z; q[3] = base + a.w;
        q[4] = base + c.x; q[5] = base + c.y; q[6] = base + c.z; q[7] = base + c.w;
    }
    float isq[8], itq[8];
#pragma unroll
    for (int j = 0; j < 8; ++j) { isq[j] = inv_s[q[j]]; itq[j] = inv_t[q[j]]; }
    const float isn = inv_s[p];
    const float itn = inv_t[p];
    const float4* srow = (const float4*)(s + (size_t)p * DD);
    const float4* trow = (const float4*)(t + (size_t)p * DD);
    float4 as0 = srow[lane], as1 = srow[lane + 64], as2 = srow[lane + 128];
    float4 at0 = trow[lane], at1 = trow[lane + 64], at2 = trow[lane + 128];
    float ds[8], dt[8];
#pragma unroll
    for (int j = 0; j < 8; ++j) {
        const float4* snb = (const float4*)(s + (size_t)q[j] * DD);
        const float4* tnb = (const float4*)(t + (size_t)q[j] * DD);
        float4 v0 = snb[lane], v1 = snb[lane + 64], v2 = snb[lane + 128];
        float4 w0 = tnb[lane], w1 = tnb[lane + 64], w2 = tnb[lane + 128];
        float a = 0.f, b = 0.f;
        a = fmaf(as0.x, v0.x, a); a = fmaf(as0.y, v0.y, a);
        a = fmaf(as0.z, v0.z, a); a = fmaf(as0.w, v0.w, a);
        a = fmaf(as1.x, v1.x, a); a = fmaf(as1.y, v1.y, a);
        a = fmaf(as1.z, v1.z, a); a = fmaf(as1.w, v1.w, a);
        a = fmaf(as2.x, v2.x, a); a = fmaf(as2.y, v2.y, a);
        a = fmaf(as2.z, v2.z, a); a = fmaf(as2.w, v2.w, a);
        b = fmaf(at0.x, w0.x, b); b = fmaf(at0.y, w0.y, b);
        b = fmaf(at0.z, w0.z, b); b = fmaf(at0.w, w0.w, b);
        b = fmaf(at1.x, w1.x, b); b = fmaf(at1.y, w1.y, b);
        b = fmaf(at1.z, w1.z, b); b = fmaf(at1.w, w1.w, b);
        b = fmaf(at2.x, w2.x, b); b = fmaf(at2.y, w2.y, b);
        b = fmaf(at2.z, w2.z, b); b = fmaf(at2.w, w2.w, b);
        ds[j] = a; dt[j] = b;
    }
#pragma unroll
    for (int m = 1; m < 64; m <<= 1) {
#pragma unroll
        for (int j = 0; j < 8; ++j) {
            ds[j] += __shfl_xor(ds[j], m);
            dt[j] += __shfl_xor(dt[j], m);
        }
    }
    float sum = 0.f;
#pragma unroll
    for (int j = 0; j < 8; ++j) {
        const float cs   = ds[j] * isn * isq[j];
        const float ct   = dt[j] * itn * itq[j];
        const float diff = fabsf(cs - ct);
        sum += diff < BETA_F ? (0.5f * diff * diff / BETA_F) : (diff - 0.5f * BETA_F);
    }
    __shared__ float wpart[4];
    if (lane == 0) wpart[wave] = sum;
    __syncthreads();
    if (threadIdx.x == 0)
        part[blockIdx.x] = (wpart[0] + wpart[1]) + (wpart[2] + wpart[3]);
}

// ---------------------------------------------------------------------------
// finalize: deterministic tree reduce of 4096 block partials + final scale.
// ---------------------------------------------------------------------------
__global__ __launch_bounds__(256) void finalize_kernel(const float* __restrict__ part,
                                                       float* __restrict__ out) {
    __shared__ float red[256];
    float acc = 0.f;
    for (int i = threadIdx.x; i < (BB * NN) / 4; i += 256) acc += part[i];
    red[threadIdx.x] = acc;
    __syncthreads();
    for (int off = 128; off > 0; off >>= 1) {
        if (threadIdx.x < off) red[threadIdx.x] += red[threadIdx.x + off];
        __syncthreads();
    }
    if (threadIdx.x == 0) out[0] = red[0] * (1.0f / (float)(BB * NN * KK));
}

extern "C" void kernel_launch(void* const* d_in, const int* in_sizes, int n_in,
                              void* d_out, int out_size, void* d_ws, size_t ws_size,
                              hipStream_t stream) {
    const float* student = (const float*)d_in[0];
    const float* teacher = (const float*)d_in[1];
    const float* centers = (const float*)d_in[2];
    float* out = (float*)d_out;

    const size_t idx_bytes  = (size_t)BB * NN * KK * sizeof(int);      // 512 KB
    const size_t half_bytes = (size_t)BB * NN * DD * sizeof(__half);   // 25.2 MB
    const size_t part_bytes = 4096 * sizeof(float);
    int* idx_buf = (int*)d_ws;

    if (ws_size >= idx_bytes + 2 * half_bytes + part_bytes) {
        __half* ns  = (__half*)((char*)d_ws + idx_bytes);
        __half* nt  = ns + (size_t)BB * NN * DD;
        float* part = (float*)((char*)d_ws + idx_bytes + 2 * half_bytes);
        fused_prep<<<TPK_BLOCKS + NORM_BLOCKS, 256, 0, stream>>>(centers, student,
                                                                 teacher, idx_buf, ns, nt);
        lossh_kernel<<<NORM_BLOCKS, 256, 0, stream>>>(ns, nt, idx_buf, part);
        finalize_kernel<<<1, 256, 0, stream>>>(part, out);
    } else {
        float* inv_s = (float*)((char*)d_ws + idx_bytes);
        float* inv_t = inv_s + BB * NN;
        float* part  = inv_t + BB * NN;
        topk_kernel<<<TPK_BLOCKS, 256, 0, stream>>>(centers, idx_buf);
        norm_kernel<<<NORM_BLOCKS, 256, 0, stream>>>(student, teacher, inv_s, inv_t);
        lossf_kernel<<<NORM_BLOCKS, 256, 0, stream>>>(student, teacher, idx_buf,
                                                      inv_s, inv_t, part);
        finalize_kernel<<<1, 256, 0, stream>>>(part, out);
    }
}